// Round 9
// baseline (289.622 us; speedup 1.0000x reference)
//
#include <hip/hip_runtime.h>
#include <stdint.h>

// GIN layer, f32 interface. bf16 MFMA GEMMs with BN-stat epilogues.
// R9: edge binning via LDS-staged counting sort (k_bin): block-local LDS
// histogram over all 1563 buckets, ONE global atomicAdd per (block,bucket)
// cell (~100k atomics vs 800k per-edge: R8 showed per-lane atomic service
// throughput ~40us/800k is the floor, independent of contention).
// Bucket regions are contiguous; aggmax reads one range per bucket.
// Partial maxes: packed bf16, 0xFF80 = -inf sentinel; agg-combine fused
// into gemm1 A-load; BN1+ReLU fused into gemm2 A-load. partials in
// [block][256] layout (coalesced epilogue stores).

#define NN 50000
#define NE 800000
#define DD 128
#define BN_EPS 1e-5f
#define NB 1563    // ceil(50000/32) buckets (32 dst nodes each)
#define CAPB 768   // bucket region capacity: mean 512 + ~11 sigma
#define NBK 64     // binning blocks
#define EPB 12500  // edges per binning block (64*12500 = 800000)

typedef short bf16x8 __attribute__((ext_vector_type(8)));
typedef float f32x4 __attribute__((ext_vector_type(4)));

__device__ __forceinline__ float bf2f(unsigned short u) {
    return __uint_as_float(((unsigned int)u) << 16);
}
__device__ __forceinline__ unsigned short f2bf(float f) {
    unsigned int u = __float_as_uint(f);
    u += 0x7fffu + ((u >> 16) & 1u);  // RNE
    return (unsigned short)(u >> 16);
}
__device__ __forceinline__ float plo(unsigned int p) { return bf2f((unsigned short)(p & 0xffffu)); }
__device__ __forceinline__ float phi(unsigned int p) { return bf2f((unsigned short)(p >> 16)); }
// monotone f32<->u32 encoding: order-preserving; never produces 0
__device__ __forceinline__ unsigned int encf(float f) {
    unsigned int b = __float_as_uint(f);
    return (b & 0x80000000u) ? ~b : (b | 0x80000000u);
}
__device__ __forceinline__ float decf(unsigned int e) {
    return __uint_as_float((e & 0x80000000u) ? (e ^ 0x80000000u) : ~e);
}

// ---- W1,W2 transpose -> bf16; init line-padded bucket cursors ----
__global__ __launch_bounds__(256) void k_init(
    const float* __restrict__ W1, const float* __restrict__ W2,
    unsigned short* __restrict__ Wt1, unsigned short* __restrict__ Wt2,
    unsigned int* __restrict__ bcur)
{
    int g = blockIdx.x * 256 + threadIdx.x;  // 0..32767
    if (g < 16384) {
        int row = g >> 7, col = g & 127;
        Wt1[col * DD + row] = f2bf(W1[g]);
    } else if (g < 32768) {
        int h = g - 16384;
        int row = h >> 7, col = h & 127;
        Wt2[col * DD + row] = f2bf(W2[h]);
    }
    if (g < NB) bcur[(size_t)g * 16] = (unsigned int)g * CAPB;
}

// ---- feats f32 -> bf16 packed (pure streaming) ----
__global__ __launch_bounds__(256) void k_feat16(const float* __restrict__ feats,
                                                unsigned int* __restrict__ fb)
{
    int g = blockIdx.x * 256 + threadIdx.x;   // 1.6M threads, 4 floats each
    float4 v = *reinterpret_cast<const float4*>(feats + (size_t)g * 4);
    uint2 o;
    o.x = (unsigned int)f2bf(v.x) | ((unsigned int)f2bf(v.y) << 16);
    o.y = (unsigned int)f2bf(v.z) | ((unsigned int)f2bf(v.w) << 16);
    *reinterpret_cast<uint2*>(fb + (size_t)g * 2) = o;
}

// ---- edge binning: LDS-staged counting sort, 1 atomic per (block,bucket) ----
// word = src<<16 | dst (both < 65536). bucket = dst>>5.
__global__ __launch_bounds__(256) void k_bin(
    const int* __restrict__ src, const int* __restrict__ dst,
    unsigned int* __restrict__ bcur, unsigned int* __restrict__ tmp)
{
    __shared__ unsigned int words[EPB];
    __shared__ unsigned short loff[EPB];
    __shared__ unsigned int lhist[NB];
    __shared__ unsigned int lbase[NB];
    int tid = threadIdx.x;
    int e0 = blockIdx.x * EPB;
    for (int c = tid; c < NB; c += 256) lhist[c] = 0u;
    __syncthreads();
    for (int i = tid; i < EPB; i += 256) {
        int d = dst[e0 + i];
        int s = src[e0 + i];
        words[i] = ((unsigned int)s << 16) | (unsigned int)d;
        loff[i] = (unsigned short)atomicAdd(&lhist[d >> 5], 1u);
    }
    __syncthreads();
    for (int c = tid; c < NB; c += 256) {
        unsigned int cnt = lhist[c];
        lbase[c] = cnt ? atomicAdd(&bcur[(size_t)c * 16], cnt) : 0u;
    }
    __syncthreads();
    for (int i = tid; i < EPB; i += 256) {
        unsigned int w = words[i];
        int b = (int)((w & 0xffffu) >> 5);
        unsigned int pos = lbase[b] + (unsigned int)loff[i];
        if (pos < (unsigned int)(b + 1) * CAPB) tmp[pos] = w;
    }
}

// ---- per-half-bucket LDS max -> packed bf16 partial (0xFF80 = -inf) ----
// grid = NB*2; bucket region [b*CAPB, bcur[b]) is contiguous; the 8 logical
// waves (2 blocks x 4) stride it in 64-edge chunks.
__global__ __launch_bounds__(256) void k_aggmax(
    const unsigned int* __restrict__ F,   // fb as uint rows of 64
    const unsigned int* __restrict__ tmp,
    const unsigned int* __restrict__ bcur,
    unsigned int* __restrict__ part0,
    unsigned int* __restrict__ part1)
{
    __shared__ unsigned int mx[32 * 128];  // [node][0..63]=lo, [64..127]=hi
    int tid = threadIdx.x;
    int b = blockIdx.x >> 1;
    int half = blockIdx.x & 1;
    int n0 = b * 32;
    unsigned int* __restrict__ part = half ? part1 : part0;
    for (int i = tid; i < 32 * 128; i += 256) mx[i] = 0u;  // 0 = -inf
    __syncthreads();

    int wave = tid >> 6, lane = tid & 63;
    unsigned int base = (unsigned int)b * CAPB;
    unsigned int cnt = bcur[(size_t)b * 16] - base;
    if (cnt > CAPB) cnt = CAPB;

    for (unsigned int start = (unsigned int)(half * 4 + wave) * 64; start < cnt; start += 512) {
        int nw = (int)(cnt - start) < 64 ? (int)(cnt - start) : 64;
        unsigned int pw = (lane < nw) ? tmp[base + start + lane] : 0u;
        int j = 0;
        for (; j + 8 <= nw; j += 8) {
            unsigned int e0 = __shfl(pw, j + 0);
            unsigned int e1 = __shfl(pw, j + 1);
            unsigned int e2 = __shfl(pw, j + 2);
            unsigned int e3 = __shfl(pw, j + 3);
            unsigned int e4 = __shfl(pw, j + 4);
            unsigned int e5 = __shfl(pw, j + 5);
            unsigned int e6 = __shfl(pw, j + 6);
            unsigned int e7 = __shfl(pw, j + 7);
            unsigned int u0 = F[(e0 >> 16) * 64 + lane];
            unsigned int u1 = F[(e1 >> 16) * 64 + lane];
            unsigned int u2 = F[(e2 >> 16) * 64 + lane];
            unsigned int u3 = F[(e3 >> 16) * 64 + lane];
            unsigned int u4 = F[(e4 >> 16) * 64 + lane];
            unsigned int u5 = F[(e5 >> 16) * 64 + lane];
            unsigned int u6 = F[(e6 >> 16) * 64 + lane];
            unsigned int u7 = F[(e7 >> 16) * 64 + lane];
            int d0 = (e0 & 31) << 7, d1 = (e1 & 31) << 7;
            int d2 = (e2 & 31) << 7, d3 = (e3 & 31) << 7;
            int d4 = (e4 & 31) << 7, d5 = (e5 & 31) << 7;
            int d6 = (e6 & 31) << 7, d7 = (e7 & 31) << 7;
            atomicMax(&mx[d0 + lane], encf(plo(u0)));
            atomicMax(&mx[d0 + 64 + lane], encf(phi(u0)));
            atomicMax(&mx[d1 + lane], encf(plo(u1)));
            atomicMax(&mx[d1 + 64 + lane], encf(phi(u1)));
            atomicMax(&mx[d2 + lane], encf(plo(u2)));
            atomicMax(&mx[d2 + 64 + lane], encf(phi(u2)));
            atomicMax(&mx[d3 + lane], encf(plo(u3)));
            atomicMax(&mx[d3 + 64 + lane], encf(phi(u3)));
            atomicMax(&mx[d4 + lane], encf(plo(u4)));
            atomicMax(&mx[d4 + 64 + lane], encf(phi(u4)));
            atomicMax(&mx[d5 + lane], encf(plo(u5)));
            atomicMax(&mx[d5 + 64 + lane], encf(phi(u5)));
            atomicMax(&mx[d6 + lane], encf(plo(u6)));
            atomicMax(&mx[d6 + 64 + lane], encf(phi(u6)));
            atomicMax(&mx[d7 + lane], encf(plo(u7)));
            atomicMax(&mx[d7 + 64 + lane], encf(phi(u7)));
        }
        for (; j < nw; ++j) {
            unsigned int e = __shfl(pw, j);
            unsigned int u = F[(e >> 16) * 64 + lane];
            int d = (e & 31) << 7;
            atomicMax(&mx[d + lane], encf(plo(u)));
            atomicMax(&mx[d + 64 + lane], encf(phi(u)));
        }
    }
    __syncthreads();

    // partial max -> packed bf16 (exact: values are bf16-representable)
    for (int idx2 = tid; idx2 < 32 * 64; idx2 += 256) {
        int node = idx2 >> 6, j = idx2 & 63;
        int n = n0 + node;
        if (n >= NN) continue;
        unsigned int e0 = mx[node * 128 + j];
        unsigned int e1 = mx[node * 128 + 64 + j];
        unsigned int lo16 = (e0 == 0u) ? 0xFF80u : (unsigned int)f2bf(decf(e0));
        unsigned int hi16 = (e1 == 0u) ? 0xFF80u : (unsigned int)f2bf(decf(e1));
        part[n * 64 + j] = lo16 | (hi16 << 16);
    }
}

// ---- GEMM: Y = act(X) @ W + b (bf16 MFMA) + per-column sum/sumsq ----
// MODE 1: A = relu(pa[k]*x + pc[k])        (layer-2: BN1+ReLU on load)
// MODE 2: A = fb + max0(max(part0,part1))  (layer-1: agg combine on load)
// block = 256 thr; 32 rows; wave = 16 rows x 64 cols.
// mfma_f32_16x16x32_bf16: A[m=lane&15][k=quad*8+j], B[n=lane&15][k=quad*8+j],
// C/D: col=lane&15, row=quad*4+reg (m89-verified).
template <int MODE>
__global__ __launch_bounds__(256) void k_gemm(
    const unsigned short* __restrict__ X, const unsigned int* __restrict__ fbp,
    const unsigned int* __restrict__ p0, const unsigned int* __restrict__ p1,
    const unsigned short* __restrict__ Wt, const float* __restrict__ bias,
    const float* __restrict__ pa, const float* __restrict__ pc,
    unsigned short* __restrict__ Y, float* __restrict__ partials)
{
    __shared__ float lsum[128], lsq[128];
    int tid = threadIdx.x;
    if (tid < 128) { lsum[tid] = 0.f; lsq[tid] = 0.f; }
    __syncthreads();
    int wave = tid >> 6, lane = tid & 63;
    int quad = lane >> 4, l16 = lane & 15;
    int m0 = blockIdx.x * 32 + (wave >> 1) * 16;
    int nh = (wave & 1) * 64;
    int myrow = m0 + l16;
    int kq = quad * 8;

    f32x4 acc[4];
#pragma unroll
    for (int j = 0; j < 4; ++j)
#pragma unroll
        for (int r = 0; r < 4; ++r) acc[j][r] = 0.f;

#pragma unroll
    for (int k0 = 0; k0 < 128; k0 += 32) {
        bf16x8 a;
        if (myrow < NN) {
            if (MODE == 2) {
                int uoff = myrow * 64 + ((k0 + kq) >> 1);
                uint4 xv = *reinterpret_cast<const uint4*>(fbp + uoff);
                uint4 q0 = *reinterpret_cast<const uint4*>(p0 + uoff);
                uint4 q1 = *reinterpret_cast<const uint4*>(p1 + uoff);
                unsigned int xs[4] = {xv.x, xv.y, xv.z, xv.w};
                unsigned int a0[4] = {q0.x, q0.y, q0.z, q0.w};
                unsigned int a1[4] = {q1.x, q1.y, q1.z, q1.w};
#pragma unroll
                for (int t = 0; t < 4; ++t) {
                    float mlo = fmaxf(plo(a0[t]), plo(a1[t]));
                    float mhi = fmaxf(phi(a0[t]), phi(a1[t]));
                    if (mlo < -3.0e38f) mlo = 0.f;   // both -inf: no in-edges
                    if (mhi < -3.0e38f) mhi = 0.f;
                    a[2 * t] = (short)f2bf(plo(xs[t]) + mlo);
                    a[2 * t + 1] = (short)f2bf(phi(xs[t]) + mhi);
                }
            } else {
                a = *reinterpret_cast<const bf16x8*>(X + myrow * DD + k0 + kq);
                float4 av0 = *reinterpret_cast<const float4*>(pa + k0 + kq);
                float4 av1 = *reinterpret_cast<const float4*>(pa + k0 + kq + 4);
                float4 cv0 = *reinterpret_cast<const float4*>(pc + k0 + kq);
                float4 cv1 = *reinterpret_cast<const float4*>(pc + k0 + kq + 4);
                float fa[8] = {av0.x, av0.y, av0.z, av0.w, av1.x, av1.y, av1.z, av1.w};
                float fc[8] = {cv0.x, cv0.y, cv0.z, cv0.w, cv1.x, cv1.y, cv1.z, cv1.w};
#pragma unroll
                for (int j = 0; j < 8; ++j) {
                    float v = fmaxf(fa[j] * bf2f((unsigned short)a[j]) + fc[j], 0.f);
                    a[j] = (short)f2bf(v);
                }
            }
        } else {
#pragma unroll
            for (int j = 0; j < 8; ++j) a[j] = 0;
        }
#pragma unroll
        for (int j = 0; j < 4; ++j) {
            bf16x8 bb = *reinterpret_cast<const bf16x8*>(Wt + (nh + j * 16 + l16) * DD + k0 + kq);
            acc[j] = __builtin_amdgcn_mfma_f32_16x16x32_bf16(a, bb, acc[j], 0, 0, 0);
        }
    }

    int rbase = m0 + quad * 4;
#pragma unroll
    for (int j = 0; j < 4; ++j) {
        int col = nh + j * 16 + l16;
        float bcol = bias[col];
        float s = 0.f, q = 0.f;
#pragma unroll
        for (int r = 0; r < 4; ++r) {
            int row = rbase + r;
            if (row < NN) {
                float v = acc[j][r] + bcol;
                Y[row * DD + col] = f2bf(v);
                s += v;
                q += v * v;
            }
        }
        s += __shfl_xor(s, 16, 64);
        s += __shfl_xor(s, 32, 64);
        q += __shfl_xor(q, 16, 64);
        q += __shfl_xor(q, 32, 64);
        if (quad == 0) {
            atomicAdd(&lsum[col], s);
            atomicAdd(&lsq[col], q);
        }
    }
    __syncthreads();
    // coalesced 1KB store: partials[block][0..127]=sum, [128..255]=sumsq
    if (tid < 128) {
        partials[blockIdx.x * 256 + tid] = lsum[tid];
        partials[blockIdx.x * 256 + 128 + tid] = lsq[tid];
    }
}

// ---- reduce partials + BN affine: a = g*rsqrt(var+eps), c = be - mean*a ----
__global__ void k_redparams(const float* __restrict__ partials, int nblk,
                            const float* __restrict__ g, const float* __restrict__ be,
                            float* __restrict__ a, float* __restrict__ c) {
    __shared__ float ls[256], lq[256];
    int t = threadIdx.x;
    int col = blockIdx.x;  // 0..127
    float s = 0.f, q = 0.f;
    for (int i = t; i < nblk; i += 256) {
        s += partials[i * 256 + col];
        q += partials[i * 256 + 128 + col];
    }
    ls[t] = s; lq[t] = q;
    __syncthreads();
    for (int off = 128; off > 0; off >>= 1) {
        if (t < off) { ls[t] += ls[t + off]; lq[t] += lq[t + off]; }
        __syncthreads();
    }
    if (t == 0) {
        float mean = ls[0] / (float)NN;
        float var = fmaxf(lq[0] / (float)NN - mean * mean, 0.f);
        float av = g[col] * rsqrtf(var + BN_EPS);
        a[col] = av;
        c[col] = be[col] - mean * av;
    }
}

// ---- stats of z = relu(a2*Y2 + c2) ----
__global__ __launch_bounds__(256) void k_zstats(
    const unsigned short* __restrict__ Y2, const float* __restrict__ a2,
    const float* __restrict__ c2, float* __restrict__ partials)
{
    __shared__ float ls[256], lq[256];
    int t = threadIdx.x;
    int col = t & 127, half = t >> 7;
    float av = a2[col], cv = c2[col];
    float s = 0.f, q = 0.f;
    for (int row = blockIdx.x * 2 + half; row < NN; row += gridDim.x * 2) {
        float z = fmaxf(av * bf2f(Y2[row * DD + col]) + cv, 0.f);
        s += z;
        q += z * z;
    }
    ls[t] = s;
    lq[t] = q;
    __syncthreads();
    if (t < 128) {
        partials[blockIdx.x * 256 + t] = ls[t] + ls[t + 128];
        partials[blockIdx.x * 256 + 128 + t] = lq[t] + lq[t + 128];
    }
}

// ---- out = a3*relu(a2*Y2+c2) + c3, f32 out ----
__global__ __launch_bounds__(256) void k_out(
    const unsigned short* __restrict__ Y2, const float* __restrict__ a2,
    const float* __restrict__ c2, const float* __restrict__ a3,
    const float* __restrict__ c3, float* __restrict__ out)
{
    int g = blockIdx.x * 256 + threadIdx.x;
    int base = g * 4;
    int c0 = base & 127;
    uint2 p = *reinterpret_cast<const uint2*>(Y2 + base);
    float4 av2 = *reinterpret_cast<const float4*>(a2 + c0);
    float4 cv2 = *reinterpret_cast<const float4*>(c2 + c0);
    float4 av3 = *reinterpret_cast<const float4*>(a3 + c0);
    float4 cv3 = *reinterpret_cast<const float4*>(c3 + c0);
    float z0 = fmaxf(av2.x * plo(p.x) + cv2.x, 0.f);
    float z1 = fmaxf(av2.y * phi(p.x) + cv2.y, 0.f);
    float z2 = fmaxf(av2.z * plo(p.y) + cv2.z, 0.f);
    float z3 = fmaxf(av2.w * phi(p.y) + cv2.w, 0.f);
    float4 o;
    o.x = av3.x * z0 + cv3.x;
    o.y = av3.y * z1 + cv3.y;
    o.z = av3.z * z2 + cv3.z;
    o.w = av3.w * z3 + cv3.w;
    *reinterpret_cast<float4*>(out + base) = o;
}

extern "C" void kernel_launch(void* const* d_in, const int* in_sizes, int n_in,
                              void* d_out, int out_size, void* d_ws, size_t ws_size,
                              hipStream_t stream) {
    (void)in_sizes; (void)n_in; (void)out_size; (void)ws_size;
    const float* feats = (const float*)d_in[0];
    const int* src = (const int*)d_in[1];
    const int* dst = (const int*)d_in[2];
    const float* W1 = (const float*)d_in[3];
    const float* b1 = (const float*)d_in[4];
    const float* g1 = (const float*)d_in[5];
    const float* be1 = (const float*)d_in[6];
    const float* W2 = (const float*)d_in[7];
    const float* b2 = (const float*)d_in[8];
    const float* g2 = (const float*)d_in[9];
    const float* be2 = (const float*)d_in[10];
    const float* g3 = (const float*)d_in[11];
    const float* be3 = (const float*)d_in[12];
    float* out = (float*)d_out;

    char* p = (char*)d_ws;
    auto alloc = [&](size_t n) { char* r = p; p += (n + 255) & ~(size_t)255; return r; };
    unsigned int* fb = (unsigned int*)alloc((size_t)NN * 64 * 4);      // packed bf16
    unsigned int* part0 = (unsigned int*)alloc((size_t)NN * 64 * 4);   // packed bf16
    unsigned int* part1 = (unsigned int*)alloc((size_t)NN * 64 * 4);   // packed bf16
    unsigned int* bcur = (unsigned int*)alloc((size_t)NB * 16 * 4);    // line-padded
    unsigned int* tmp = (unsigned int*)alloc((size_t)NB * CAPB * 4);
    unsigned short* Y1 = (unsigned short*)alloc((size_t)NN * DD * 2);
    unsigned short* Y2 = (unsigned short*)alloc((size_t)NN * DD * 2);
    unsigned short* Wt1 = (unsigned short*)alloc((size_t)DD * DD * 2);
    unsigned short* Wt2 = (unsigned short*)alloc((size_t)DD * DD * 2);
    float* partials = (float*)alloc((size_t)1568 * 256 * 4);
    float* a1 = (float*)alloc(DD * 4); float* c1 = (float*)alloc(DD * 4);
    float* a2 = (float*)alloc(DD * 4); float* c2 = (float*)alloc(DD * 4);
    float* a3 = (float*)alloc(DD * 4); float* c3 = (float*)alloc(DD * 4);

    k_init<<<128, 256, 0, stream>>>(W1, W2, Wt1, Wt2, bcur);
    k_feat16<<<6250, 256, 0, stream>>>(feats, fb);
    k_bin<<<NBK, 256, 0, stream>>>(src, dst, bcur, tmp);
    k_aggmax<<<NB * 2, 256, 0, stream>>>(fb, tmp, bcur, part0, part1);
    // layer 1 (agg combine + feats add fused into A-load)
    k_gemm<2><<<1563, 256, 0, stream>>>(nullptr, fb, part0, part1, Wt1, b1,
                                        nullptr, nullptr, Y1, partials);
    k_redparams<<<128, 256, 0, stream>>>(partials, 1563, g1, be1, a1, c1);
    // layer 2 (BN1+ReLU fused into A-load)
    k_gemm<1><<<1563, 256, 0, stream>>>(Y1, nullptr, nullptr, nullptr, Wt2, b2,
                                        a1, c1, Y2, partials);
    k_redparams<<<128, 256, 0, stream>>>(partials, 1563, g2, be2, a2, c2);
    // outer BN over z = relu(a2*Y2+c2)
    k_zstats<<<256, 256, 0, stream>>>(Y2, a2, c2, partials);
    k_redparams<<<128, 256, 0, stream>>>(partials, 256, g3, be3, a3, c3);
    k_out<<<6250, 256, 0, stream>>>(Y2, a2, c2, a3, c3, out);
}

// Round 10
// 261.933 us; speedup vs baseline: 1.1057x; 1.1057x over previous
//
#include <hip/hip_runtime.h>
#include <stdint.h>

// GIN layer, f32 interface. bf16 MFMA GEMMs with BN-stat epilogues.
// R10: k_bin bumped to 1024 threads (R9: 256 thr x 64 blocks left 75% of
// the GPU idle); aggmax back to one 512-thread block per bucket writing
// h0 = fb + max directly (kills 25.6 MB part0/part1 round-trip and
// gemm1's combine); gemm blocks 64 rows x 512 thr (halves partials);
// k_init merged into k_prep. Counting-sort binning: 1 global atomic per
// (block,bucket) (~100k vs 800k per-edge — R8 measured per-lane atomic
// service ~40us/800k regardless of contention).

#define NN 50000
#define NE 800000
#define DD 128
#define BN_EPS 1e-5f
#define NB 1563    // ceil(50000/32) buckets (32 dst nodes each)
#define CAPB 768   // bucket region capacity: mean 512 + ~11 sigma
#define NBK 64     // binning blocks
#define EPB 12500  // edges per binning block (64*12500 = 800000)

typedef short bf16x8 __attribute__((ext_vector_type(8)));
typedef float f32x4 __attribute__((ext_vector_type(4)));

__device__ __forceinline__ float bf2f(unsigned short u) {
    return __uint_as_float(((unsigned int)u) << 16);
}
__device__ __forceinline__ unsigned short f2bf(float f) {
    unsigned int u = __float_as_uint(f);
    u += 0x7fffu + ((u >> 16) & 1u);  // RNE
    return (unsigned short)(u >> 16);
}
__device__ __forceinline__ float plo(unsigned int p) { return bf2f((unsigned short)(p & 0xffffu)); }
__device__ __forceinline__ float phi(unsigned int p) { return bf2f((unsigned short)(p >> 16)); }
// monotone f32<->u32 encoding: order-preserving; never produces 0
__device__ __forceinline__ unsigned int encf(float f) {
    unsigned int b = __float_as_uint(f);
    return (b & 0x80000000u) ? ~b : (b | 0x80000000u);
}
__device__ __forceinline__ float decf(unsigned int e) {
    return __uint_as_float((e & 0x80000000u) ? (e ^ 0x80000000u) : ~e);
}

// ---- feats f32 -> bf16 packed; W transposes; cursor init (one launch) ----
__global__ __launch_bounds__(256) void k_prep(
    const float* __restrict__ feats, unsigned int* __restrict__ fb,
    const float* __restrict__ W1, const float* __restrict__ W2,
    unsigned short* __restrict__ Wt1, unsigned short* __restrict__ Wt2,
    unsigned int* __restrict__ bcur)
{
    int g = blockIdx.x * 256 + threadIdx.x;   // 1.6M threads, 4 floats each
    float4 v = *reinterpret_cast<const float4*>(feats + (size_t)g * 4);
    uint2 o;
    o.x = (unsigned int)f2bf(v.x) | ((unsigned int)f2bf(v.y) << 16);
    o.y = (unsigned int)f2bf(v.z) | ((unsigned int)f2bf(v.w) << 16);
    *reinterpret_cast<uint2*>(fb + (size_t)g * 2) = o;
    if (g < 16384) {
        int row = g >> 7, col = g & 127;
        Wt1[col * DD + row] = f2bf(W1[g]);
    } else if (g < 32768) {
        int h = g - 16384;
        int row = h >> 7, col = h & 127;
        Wt2[col * DD + row] = f2bf(W2[h]);
    }
    if (g < NB) bcur[(size_t)g * 16] = (unsigned int)g * CAPB;
}

// ---- edge binning: LDS-staged counting sort, 1 atomic per (block,bucket) ----
// word = src<<16 | dst (both < 65536). bucket = dst>>5. 1024 threads.
__global__ __launch_bounds__(1024) void k_bin(
    const int* __restrict__ src, const int* __restrict__ dst,
    unsigned int* __restrict__ bcur, unsigned int* __restrict__ tmp)
{
    __shared__ unsigned int words[EPB];
    __shared__ unsigned short loff[EPB];
    __shared__ unsigned int lhist[NB];
    __shared__ unsigned int lbase[NB];
    int tid = threadIdx.x;
    int e0 = blockIdx.x * EPB;
    for (int c = tid; c < NB; c += 1024) lhist[c] = 0u;
    __syncthreads();
    for (int i = tid; i < EPB; i += 1024) {
        int d = dst[e0 + i];
        int s = src[e0 + i];
        words[i] = ((unsigned int)s << 16) | (unsigned int)d;
        loff[i] = (unsigned short)atomicAdd(&lhist[d >> 5], 1u);
    }
    __syncthreads();
    for (int c = tid; c < NB; c += 1024) {
        unsigned int cnt = lhist[c];
        lbase[c] = cnt ? atomicAdd(&bcur[(size_t)c * 16], cnt) : 0u;
    }
    __syncthreads();
    for (int i = tid; i < EPB; i += 1024) {
        unsigned int w = words[i];
        int b = (int)((w & 0xffffu) >> 5);
        unsigned int pos = lbase[b] + (unsigned int)loff[i];
        if (pos < (unsigned int)(b + 1) * CAPB) tmp[pos] = w;
    }
}

// ---- per-bucket LDS max; writes h0 = fb + max0(agg) directly ----
// grid = NB, 512 threads = 8 waves; wave w strides the bucket's contiguous
// region in 64-edge chunks (coalesced word load + shfl broadcast).
__global__ __launch_bounds__(512) void k_aggmax(
    const unsigned int* __restrict__ F,   // fb as uint rows of 64
    const unsigned int* __restrict__ tmp,
    const unsigned int* __restrict__ bcur,
    unsigned int* __restrict__ h0)        // packed bf16 rows of 64
{
    __shared__ unsigned int mx[32 * 128];  // [node][0..63]=lo, [64..127]=hi
    int tid = threadIdx.x;
    int b = blockIdx.x;
    int n0 = b * 32;
    for (int i = tid; i < 32 * 128; i += 512) mx[i] = 0u;  // 0 = -inf
    __syncthreads();

    int wave = tid >> 6, lane = tid & 63;
    unsigned int base = (unsigned int)b * CAPB;
    unsigned int cnt = bcur[(size_t)b * 16] - base;
    if (cnt > CAPB) cnt = CAPB;

    for (unsigned int start = (unsigned int)wave * 64; start < cnt; start += 512) {
        int nw = (int)(cnt - start) < 64 ? (int)(cnt - start) : 64;
        unsigned int pw = (lane < nw) ? tmp[base + start + lane] : 0u;
        int j = 0;
        for (; j + 8 <= nw; j += 8) {
            unsigned int e0 = __shfl(pw, j + 0);
            unsigned int e1 = __shfl(pw, j + 1);
            unsigned int e2 = __shfl(pw, j + 2);
            unsigned int e3 = __shfl(pw, j + 3);
            unsigned int e4 = __shfl(pw, j + 4);
            unsigned int e5 = __shfl(pw, j + 5);
            unsigned int e6 = __shfl(pw, j + 6);
            unsigned int e7 = __shfl(pw, j + 7);
            unsigned int u0 = F[(e0 >> 16) * 64 + lane];
            unsigned int u1 = F[(e1 >> 16) * 64 + lane];
            unsigned int u2 = F[(e2 >> 16) * 64 + lane];
            unsigned int u3 = F[(e3 >> 16) * 64 + lane];
            unsigned int u4 = F[(e4 >> 16) * 64 + lane];
            unsigned int u5 = F[(e5 >> 16) * 64 + lane];
            unsigned int u6 = F[(e6 >> 16) * 64 + lane];
            unsigned int u7 = F[(e7 >> 16) * 64 + lane];
            int d0 = (e0 & 31) << 7, d1 = (e1 & 31) << 7;
            int d2 = (e2 & 31) << 7, d3 = (e3 & 31) << 7;
            int d4 = (e4 & 31) << 7, d5 = (e5 & 31) << 7;
            int d6 = (e6 & 31) << 7, d7 = (e7 & 31) << 7;
            atomicMax(&mx[d0 + lane], encf(plo(u0)));
            atomicMax(&mx[d0 + 64 + lane], encf(phi(u0)));
            atomicMax(&mx[d1 + lane], encf(plo(u1)));
            atomicMax(&mx[d1 + 64 + lane], encf(phi(u1)));
            atomicMax(&mx[d2 + lane], encf(plo(u2)));
            atomicMax(&mx[d2 + 64 + lane], encf(phi(u2)));
            atomicMax(&mx[d3 + lane], encf(plo(u3)));
            atomicMax(&mx[d3 + 64 + lane], encf(phi(u3)));
            atomicMax(&mx[d4 + lane], encf(plo(u4)));
            atomicMax(&mx[d4 + 64 + lane], encf(phi(u4)));
            atomicMax(&mx[d5 + lane], encf(plo(u5)));
            atomicMax(&mx[d5 + 64 + lane], encf(phi(u5)));
            atomicMax(&mx[d6 + lane], encf(plo(u6)));
            atomicMax(&mx[d6 + 64 + lane], encf(phi(u6)));
            atomicMax(&mx[d7 + lane], encf(plo(u7)));
            atomicMax(&mx[d7 + 64 + lane], encf(phi(u7)));
        }
        for (; j < nw; ++j) {
            unsigned int e = __shfl(pw, j);
            unsigned int u = F[(e >> 16) * 64 + lane];
            int d = (e & 31) << 7;
            atomicMax(&mx[d + lane], encf(plo(u)));
            atomicMax(&mx[d + 64 + lane], encf(phi(u)));
        }
    }
    __syncthreads();

    // h0[n] = fb[n] + (deg ? max : 0), packed bf16
    for (int idx2 = tid; idx2 < 32 * 64; idx2 += 512) {
        int node = idx2 >> 6, j = idx2 & 63;
        int n = n0 + node;
        if (n >= NN) continue;
        unsigned int e0 = mx[node * 128 + j];
        unsigned int e1 = mx[node * 128 + 64 + j];
        float m0 = (e0 == 0u) ? 0.f : decf(e0);
        float m1 = (e1 == 0u) ? 0.f : decf(e1);
        unsigned int pf = F[n * 64 + j];
        h0[n * 64 + j] = (unsigned int)f2bf(plo(pf) + m0) |
                         ((unsigned int)f2bf(phi(pf) + m1) << 16);
    }
}

// ---- GEMM: Y = act(X) @ W + b (bf16 MFMA) + per-column sum/sumsq ----
// FUSE=1: A = relu(pa[k]*x + pc[k]) (layer-2: BN1+ReLU on load).
// grid 782, block 512 = 8 waves; block covers 64 rows; wave = 16r x 64c.
// mfma_f32_16x16x32_bf16: A[m=lane&15][k=quad*8+j], B[n=lane&15][k=quad*8+j],
// C/D: col=lane&15, row=quad*4+reg (m89-verified).
template <int FUSE>
__global__ __launch_bounds__(512) void k_gemm(
    const unsigned short* __restrict__ X, const unsigned short* __restrict__ Wt,
    const float* __restrict__ bias, const float* __restrict__ pa,
    const float* __restrict__ pc, unsigned short* __restrict__ Y,
    float* __restrict__ partials)
{
    __shared__ float lsum[128], lsq[128];
    int tid = threadIdx.x;
    if (tid < 128) { lsum[tid] = 0.f; lsq[tid] = 0.f; }
    __syncthreads();
    int wave = tid >> 6, lane = tid & 63;
    int quad = lane >> 4, l16 = lane & 15;
    int m0 = blockIdx.x * 64 + (wave >> 1) * 16;
    int nh = (wave & 1) * 64;
    int myrow = m0 + l16;
    int kq = quad * 8;

    f32x4 acc[4];
#pragma unroll
    for (int j = 0; j < 4; ++j)
#pragma unroll
        for (int r = 0; r < 4; ++r) acc[j][r] = 0.f;

#pragma unroll
    for (int k0 = 0; k0 < 128; k0 += 32) {
        bf16x8 a;
        if (myrow < NN) {
            a = *reinterpret_cast<const bf16x8*>(X + myrow * DD + k0 + kq);
            if (FUSE) {
                float4 av0 = *reinterpret_cast<const float4*>(pa + k0 + kq);
                float4 av1 = *reinterpret_cast<const float4*>(pa + k0 + kq + 4);
                float4 cv0 = *reinterpret_cast<const float4*>(pc + k0 + kq);
                float4 cv1 = *reinterpret_cast<const float4*>(pc + k0 + kq + 4);
                float fa[8] = {av0.x, av0.y, av0.z, av0.w, av1.x, av1.y, av1.z, av1.w};
                float fc[8] = {cv0.x, cv0.y, cv0.z, cv0.w, cv1.x, cv1.y, cv1.z, cv1.w};
#pragma unroll
                for (int j = 0; j < 8; ++j) {
                    float v = fmaxf(fa[j] * bf2f((unsigned short)a[j]) + fc[j], 0.f);
                    a[j] = (short)f2bf(v);
                }
            }
        } else {
#pragma unroll
            for (int j = 0; j < 8; ++j) a[j] = 0;
        }
#pragma unroll
        for (int j = 0; j < 4; ++j) {
            bf16x8 bb = *reinterpret_cast<const bf16x8*>(Wt + (nh + j * 16 + l16) * DD + k0 + kq);
            acc[j] = __builtin_amdgcn_mfma_f32_16x16x32_bf16(a, bb, acc[j], 0, 0, 0);
        }
    }

    int rbase = m0 + quad * 4;
#pragma unroll
    for (int j = 0; j < 4; ++j) {
        int col = nh + j * 16 + l16;
        float bcol = bias[col];
        float s = 0.f, q = 0.f;
#pragma unroll
        for (int r = 0; r < 4; ++r) {
            int row = rbase + r;
            if (row < NN) {
                float v = acc[j][r] + bcol;
                Y[row * DD + col] = f2bf(v);
                s += v;
                q += v * v;
            }
        }
        s += __shfl_xor(s, 16, 64);
        s += __shfl_xor(s, 32, 64);
        q += __shfl_xor(q, 16, 64);
        q += __shfl_xor(q, 32, 64);
        if (quad == 0) {
            atomicAdd(&lsum[col], s);
            atomicAdd(&lsq[col], q);
        }
    }
    __syncthreads();
    // coalesced 1KB store: partials[block][0..127]=sum, [128..255]=sumsq
    if (tid < 128) {
        partials[blockIdx.x * 256 + tid] = lsum[tid];
        partials[blockIdx.x * 256 + 128 + tid] = lsq[tid];
    }
}

// ---- reduce partials + BN affine: a = g*rsqrt(var+eps), c = be - mean*a ----
__global__ void k_redparams(const float* __restrict__ partials, int nblk,
                            const float* __restrict__ g, const float* __restrict__ be,
                            float* __restrict__ a, float* __restrict__ c) {
    __shared__ float ls[256], lq[256];
    int t = threadIdx.x;
    int col = blockIdx.x;  // 0..127
    float s = 0.f, q = 0.f;
    for (int i = t; i < nblk; i += 256) {
        s += partials[i * 256 + col];
        q += partials[i * 256 + 128 + col];
    }
    ls[t] = s; lq[t] = q;
    __syncthreads();
    for (int off = 128; off > 0; off >>= 1) {
        if (t < off) { ls[t] += ls[t + off]; lq[t] += lq[t + off]; }
        __syncthreads();
    }
    if (t == 0) {
        float mean = ls[0] / (float)NN;
        float var = fmaxf(lq[0] / (float)NN - mean * mean, 0.f);
        float av = g[col] * rsqrtf(var + BN_EPS);
        a[col] = av;
        c[col] = be[col] - mean * av;
    }
}

// ---- stats of z = relu(a2*Y2 + c2) ----
__global__ __launch_bounds__(256) void k_zstats(
    const unsigned short* __restrict__ Y2, const float* __restrict__ a2,
    const float* __restrict__ c2, float* __restrict__ partials)
{
    __shared__ float ls[256], lq[256];
    int t = threadIdx.x;
    int col = t & 127, half = t >> 7;
    float av = a2[col], cv = c2[col];
    float s = 0.f, q = 0.f;
    for (int row = blockIdx.x * 2 + half; row < NN; row += gridDim.x * 2) {
        float z = fmaxf(av * bf2f(Y2[row * DD + col]) + cv, 0.f);
        s += z;
        q += z * z;
    }
    ls[t] = s;
    lq[t] = q;
    __syncthreads();
    if (t < 128) {
        partials[blockIdx.x * 256 + t] = ls[t] + ls[t + 128];
        partials[blockIdx.x * 256 + 128 + t] = lq[t] + lq[t + 128];
    }
}

// ---- out = a3*relu(a2*Y2+c2) + c3, f32 out ----
__global__ __launch_bounds__(256) void k_out(
    const unsigned short* __restrict__ Y2, const float* __restrict__ a2,
    const float* __restrict__ c2, const float* __restrict__ a3,
    const float* __restrict__ c3, float* __restrict__ out)
{
    int g = blockIdx.x * 256 + threadIdx.x;
    int base = g * 4;
    int c0 = base & 127;
    uint2 p = *reinterpret_cast<const uint2*>(Y2 + base);
    float4 av2 = *reinterpret_cast<const float4*>(a2 + c0);
    float4 cv2 = *reinterpret_cast<const float4*>(c2 + c0);
    float4 av3 = *reinterpret_cast<const float4*>(a3 + c0);
    float4 cv3 = *reinterpret_cast<const float4*>(c3 + c0);
    float z0 = fmaxf(av2.x * plo(p.x) + cv2.x, 0.f);
    float z1 = fmaxf(av2.y * phi(p.x) + cv2.y, 0.f);
    float z2 = fmaxf(av2.z * plo(p.y) + cv2.z, 0.f);
    float z3 = fmaxf(av2.w * phi(p.y) + cv2.w, 0.f);
    float4 o;
    o.x = av3.x * z0 + cv3.x;
    o.y = av3.y * z1 + cv3.y;
    o.z = av3.z * z2 + cv3.z;
    o.w = av3.w * z3 + cv3.w;
    *reinterpret_cast<float4*>(out + base) = o;
}

extern "C" void kernel_launch(void* const* d_in, const int* in_sizes, int n_in,
                              void* d_out, int out_size, void* d_ws, size_t ws_size,
                              hipStream_t stream) {
    (void)in_sizes; (void)n_in; (void)out_size; (void)ws_size;
    const float* feats = (const float*)d_in[0];
    const int* src = (const int*)d_in[1];
    const int* dst = (const int*)d_in[2];
    const float* W1 = (const float*)d_in[3];
    const float* b1 = (const float*)d_in[4];
    const float* g1 = (const float*)d_in[5];
    const float* be1 = (const float*)d_in[6];
    const float* W2 = (const float*)d_in[7];
    const float* b2 = (const float*)d_in[8];
    const float* g2 = (const float*)d_in[9];
    const float* be2 = (const float*)d_in[10];
    const float* g3 = (const float*)d_in[11];
    const float* be3 = (const float*)d_in[12];
    float* out = (float*)d_out;

    char* p = (char*)d_ws;
    auto alloc = [&](size_t n) { char* r = p; p += (n + 255) & ~(size_t)255; return r; };
    unsigned int* fb = (unsigned int*)alloc((size_t)NN * 64 * 4);      // packed bf16
    unsigned int* h0 = (unsigned int*)alloc((size_t)NN * 64 * 4);      // packed bf16
    unsigned int* bcur = (unsigned int*)alloc((size_t)NB * 16 * 4);    // line-padded
    unsigned int* tmp = (unsigned int*)alloc((size_t)NB * CAPB * 4);
    unsigned short* Y1 = (unsigned short*)alloc((size_t)NN * DD * 2);
    unsigned short* Y2 = (unsigned short*)alloc((size_t)NN * DD * 2);
    unsigned short* Wt1 = (unsigned short*)alloc((size_t)DD * DD * 2);
    unsigned short* Wt2 = (unsigned short*)alloc((size_t)DD * DD * 2);
    float* partials = (float*)alloc((size_t)784 * 256 * 4);
    float* a1 = (float*)alloc(DD * 4); float* c1 = (float*)alloc(DD * 4);
    float* a2 = (float*)alloc(DD * 4); float* c2 = (float*)alloc(DD * 4);
    float* a3 = (float*)alloc(DD * 4); float* c3 = (float*)alloc(DD * 4);

    k_prep<<<6250, 256, 0, stream>>>(feats, fb, W1, W2, Wt1, Wt2, bcur);
    k_bin<<<NBK, 1024, 0, stream>>>(src, dst, bcur, tmp);
    k_aggmax<<<NB, 512, 0, stream>>>(fb, tmp, bcur, h0);
    // layer 1
    k_gemm<0><<<782, 512, 0, stream>>>((const unsigned short*)h0, Wt1, b1,
                                       nullptr, nullptr, Y1, partials);
    k_redparams<<<128, 256, 0, stream>>>(partials, 782, g1, be1, a1, c1);
    // layer 2 (BN1+ReLU fused into A-load)
    k_gemm<1><<<782, 512, 0, stream>>>(Y1, Wt2, b2, a1, c1, Y2, partials);
    k_redparams<<<128, 256, 0, stream>>>(partials, 782, g2, be2, a2, c2);
    // outer BN over z = relu(a2*Y2+c2)
    k_zstats<<<256, 256, 0, stream>>>(Y2, a2, c2, partials);
    k_redparams<<<128, 256, 0, stream>>>(partials, 256, g3, be3, a3, c3);
    k_out<<<6250, 256, 0, stream>>>(Y2, a2, c2, a3, c3, out);
}

// Round 11
// 258.467 us; speedup vs baseline: 1.1205x; 1.0134x over previous
//
#include <hip/hip_runtime.h>
#include <stdint.h>

// GIN layer, f32 interface. bf16 MFMA GEMMs with BN-stat epilogues.
// R11 aggmax v3: per-bucket counting sort BY DST in LDS (32 counters),
// then one wave per 4 dst-nodes walks each dst's contiguous run keeping
// the max in REGISTERS (no LDS value-atomics, no 16KB mx array, no
// epilogue pass) and writes h0 = fb + max0 directly. R6-R10 established:
// per-lane global atomics cost ~40us/800k regardless of contention ->
// counting-sort binning with 1 atomic per (block,bucket); gather is
// L2/LLC-served (FETCH ~75MB vs 12.8MB fb).

#define NN 50000
#define NE 800000
#define DD 128
#define BN_EPS 1e-5f
#define NB 1563    // ceil(50000/32) buckets (32 dst nodes each)
#define CAPB 768   // bucket region capacity: mean 512 + ~11 sigma
#define NBK 64     // binning blocks
#define EPB 12500  // edges per binning block (64*12500 = 800000)

typedef short bf16x8 __attribute__((ext_vector_type(8)));
typedef float f32x4 __attribute__((ext_vector_type(4)));

__device__ __forceinline__ float bf2f(unsigned short u) {
    return __uint_as_float(((unsigned int)u) << 16);
}
__device__ __forceinline__ unsigned short f2bf(float f) {
    unsigned int u = __float_as_uint(f);
    u += 0x7fffu + ((u >> 16) & 1u);  // RNE
    return (unsigned short)(u >> 16);
}
__device__ __forceinline__ float plo(unsigned int p) { return bf2f((unsigned short)(p & 0xffffu)); }
__device__ __forceinline__ float phi(unsigned int p) { return bf2f((unsigned short)(p >> 16)); }

// ---- feats f32 -> bf16 packed; W transposes; cursor init (one launch) ----
__global__ __launch_bounds__(256) void k_prep(
    const float* __restrict__ feats, unsigned int* __restrict__ fb,
    const float* __restrict__ W1, const float* __restrict__ W2,
    unsigned short* __restrict__ Wt1, unsigned short* __restrict__ Wt2,
    unsigned int* __restrict__ bcur)
{
    int g = blockIdx.x * 256 + threadIdx.x;   // 1.6M threads, 4 floats each
    float4 v = *reinterpret_cast<const float4*>(feats + (size_t)g * 4);
    uint2 o;
    o.x = (unsigned int)f2bf(v.x) | ((unsigned int)f2bf(v.y) << 16);
    o.y = (unsigned int)f2bf(v.z) | ((unsigned int)f2bf(v.w) << 16);
    *reinterpret_cast<uint2*>(fb + (size_t)g * 2) = o;
    if (g < 16384) {
        int row = g >> 7, col = g & 127;
        Wt1[col * DD + row] = f2bf(W1[g]);
    } else if (g < 32768) {
        int h = g - 16384;
        int row = h >> 7, col = h & 127;
        Wt2[col * DD + row] = f2bf(W2[h]);
    }
    if (g < NB) bcur[(size_t)g * 16] = (unsigned int)g * CAPB;
}

// ---- edge binning: LDS-staged counting sort, 1 atomic per (block,bucket) ----
// word = src<<16 | dst (both < 65536). bucket = dst>>5. 1024 threads.
__global__ __launch_bounds__(1024) void k_bin(
    const int* __restrict__ src, const int* __restrict__ dst,
    unsigned int* __restrict__ bcur, unsigned int* __restrict__ tmp)
{
    __shared__ unsigned int words[EPB];
    __shared__ unsigned short loff[EPB];
    __shared__ unsigned int lhist[NB];
    __shared__ unsigned int lbase[NB];
    int tid = threadIdx.x;
    int e0 = blockIdx.x * EPB;
    for (int c = tid; c < NB; c += 1024) lhist[c] = 0u;
    __syncthreads();
    for (int i = tid; i < EPB; i += 1024) {
        int d = dst[e0 + i];
        int s = src[e0 + i];
        words[i] = ((unsigned int)s << 16) | (unsigned int)d;
        loff[i] = (unsigned short)atomicAdd(&lhist[d >> 5], 1u);
    }
    __syncthreads();
    for (int c = tid; c < NB; c += 1024) {
        unsigned int cnt = lhist[c];
        lbase[c] = cnt ? atomicAdd(&bcur[(size_t)c * 16], cnt) : 0u;
    }
    __syncthreads();
    for (int i = tid; i < EPB; i += 1024) {
        unsigned int w = words[i];
        int b = (int)((w & 0xffffu) >> 5);
        unsigned int pos = lbase[b] + (unsigned int)loff[i];
        if (pos < (unsigned int)(b + 1) * CAPB) tmp[pos] = w;
    }
}

// ---- per-bucket: sort by dst in LDS, register max per run, write h0 ----
// grid = NB, 512 threads = 8 waves; wave w owns dst-nodes 4w..4w+3.
__global__ __launch_bounds__(512) void k_aggmax(
    const unsigned int* __restrict__ F,   // fb as uint rows of 64
    const unsigned int* __restrict__ tmp,
    const unsigned int* __restrict__ bcur,
    unsigned int* __restrict__ h0)        // packed bf16 rows of 64
{
    __shared__ unsigned int sorted[CAPB];
    __shared__ unsigned int hist[32];
    __shared__ unsigned int hbase[33];
    int tid = threadIdx.x;
    int b = blockIdx.x;
    if (tid < 32) hist[tid] = 0u;
    __syncthreads();
    unsigned int rb = (unsigned int)b * CAPB;
    unsigned int cnt = bcur[(size_t)b * 16] - rb;
    if (cnt > CAPB) cnt = CAPB;

    // phase 1: load words (coalesced), LDS hist by dst&31 (each thr <=2)
    unsigned int wreg[2]; unsigned short lo[2]; int nw = 0;
    for (unsigned int i = tid; i < cnt; i += 512) {
        unsigned int ww = tmp[rb + i];
        wreg[nw] = ww;
        lo[nw] = (unsigned short)atomicAdd(&hist[ww & 31], 1u);
        nw++;
    }
    __syncthreads();
    if (tid == 0) {
        unsigned int acc = 0;
#pragma unroll
        for (int i = 0; i < 32; ++i) { hbase[i] = acc; acc += hist[i]; }
        hbase[32] = acc;
    }
    __syncthreads();
    for (int k = 0; k < nw; ++k)
        sorted[hbase[wreg[k] & 31] + (unsigned int)lo[k]] = wreg[k];
    __syncthreads();

    // phase 2: wave per 4 dsts; register max over each dst's run
    int wave = tid >> 6, lane = tid & 63;
    int n0 = b * 32;
#pragma unroll 1
    for (int dd = wave * 4; dd < wave * 4 + 4; ++dd) {
        int n = n0 + dd;
        if (n >= NN) continue;
        int st = (int)hbase[dd], en = (int)hbase[dd + 1];
        float m0 = -3.0e38f, m1 = -3.0e38f;
        int i = st;
        for (; i + 4 <= en; i += 4) {
            unsigned int w0 = sorted[i], w1 = sorted[i + 1];
            unsigned int w2 = sorted[i + 2], w3 = sorted[i + 3];
            unsigned int u0 = F[(w0 >> 16) * 64 + lane];
            unsigned int u1 = F[(w1 >> 16) * 64 + lane];
            unsigned int u2 = F[(w2 >> 16) * 64 + lane];
            unsigned int u3 = F[(w3 >> 16) * 64 + lane];
            m0 = fmaxf(m0, fmaxf(fmaxf(plo(u0), plo(u1)), fmaxf(plo(u2), plo(u3))));
            m1 = fmaxf(m1, fmaxf(fmaxf(phi(u0), phi(u1)), fmaxf(phi(u2), phi(u3))));
        }
        for (; i < en; ++i) {
            unsigned int ww = sorted[i];
            unsigned int u = F[(ww >> 16) * 64 + lane];
            m0 = fmaxf(m0, plo(u));
            m1 = fmaxf(m1, phi(u));
        }
        if (en == st) { m0 = 0.f; m1 = 0.f; }  // no in-edges -> agg = 0
        unsigned int pf = F[n * 64 + lane];
        h0[n * 64 + lane] = (unsigned int)f2bf(plo(pf) + m0) |
                            ((unsigned int)f2bf(phi(pf) + m1) << 16);
    }
}

// ---- GEMM: Y = act(X) @ W + b (bf16 MFMA) + per-column sum/sumsq ----
// FUSE=1: A = relu(pa[k]*x + pc[k]) (layer-2: BN1+ReLU on load).
// grid 782, block 512 = 8 waves; block covers 64 rows; wave = 16r x 64c.
// mfma_f32_16x16x32_bf16: A[m=lane&15][k=quad*8+j], B[n=lane&15][k=quad*8+j],
// C/D: col=lane&15, row=quad*4+reg (m89-verified).
template <int FUSE>
__global__ __launch_bounds__(512) void k_gemm(
    const unsigned short* __restrict__ X, const unsigned short* __restrict__ Wt,
    const float* __restrict__ bias, const float* __restrict__ pa,
    const float* __restrict__ pc, unsigned short* __restrict__ Y,
    float* __restrict__ partials)
{
    __shared__ float lsum[128], lsq[128];
    int tid = threadIdx.x;
    if (tid < 128) { lsum[tid] = 0.f; lsq[tid] = 0.f; }
    __syncthreads();
    int wave = tid >> 6, lane = tid & 63;
    int quad = lane >> 4, l16 = lane & 15;
    int m0 = blockIdx.x * 64 + (wave >> 1) * 16;
    int nh = (wave & 1) * 64;
    int myrow = m0 + l16;
    int kq = quad * 8;

    f32x4 acc[4];
#pragma unroll
    for (int j = 0; j < 4; ++j)
#pragma unroll
        for (int r = 0; r < 4; ++r) acc[j][r] = 0.f;

#pragma unroll
    for (int k0 = 0; k0 < 128; k0 += 32) {
        bf16x8 a;
        if (myrow < NN) {
            a = *reinterpret_cast<const bf16x8*>(X + myrow * DD + k0 + kq);
            if (FUSE) {
                float4 av0 = *reinterpret_cast<const float4*>(pa + k0 + kq);
                float4 av1 = *reinterpret_cast<const float4*>(pa + k0 + kq + 4);
                float4 cv0 = *reinterpret_cast<const float4*>(pc + k0 + kq);
                float4 cv1 = *reinterpret_cast<const float4*>(pc + k0 + kq + 4);
                float fa[8] = {av0.x, av0.y, av0.z, av0.w, av1.x, av1.y, av1.z, av1.w};
                float fc[8] = {cv0.x, cv0.y, cv0.z, cv0.w, cv1.x, cv1.y, cv1.z, cv1.w};
#pragma unroll
                for (int j = 0; j < 8; ++j) {
                    float v = fmaxf(fa[j] * bf2f((unsigned short)a[j]) + fc[j], 0.f);
                    a[j] = (short)f2bf(v);
                }
            }
        } else {
#pragma unroll
            for (int j = 0; j < 8; ++j) a[j] = 0;
        }
#pragma unroll
        for (int j = 0; j < 4; ++j) {
            bf16x8 bb = *reinterpret_cast<const bf16x8*>(Wt + (nh + j * 16 + l16) * DD + k0 + kq);
            acc[j] = __builtin_amdgcn_mfma_f32_16x16x32_bf16(a, bb, acc[j], 0, 0, 0);
        }
    }

    int rbase = m0 + quad * 4;
#pragma unroll
    for (int j = 0; j < 4; ++j) {
        int col = nh + j * 16 + l16;
        float bcol = bias[col];
        float s = 0.f, q = 0.f;
#pragma unroll
        for (int r = 0; r < 4; ++r) {
            int row = rbase + r;
            if (row < NN) {
                float v = acc[j][r] + bcol;
                Y[row * DD + col] = f2bf(v);
                s += v;
                q += v * v;
            }
        }
        s += __shfl_xor(s, 16, 64);
        s += __shfl_xor(s, 32, 64);
        q += __shfl_xor(q, 16, 64);
        q += __shfl_xor(q, 32, 64);
        if (quad == 0) {
            atomicAdd(&lsum[col], s);
            atomicAdd(&lsq[col], q);
        }
    }
    __syncthreads();
    // coalesced 1KB store: partials[block][0..127]=sum, [128..255]=sumsq
    if (tid < 128) {
        partials[blockIdx.x * 256 + tid] = lsum[tid];
        partials[blockIdx.x * 256 + 128 + tid] = lsq[tid];
    }
}

// ---- reduce partials + BN affine: a = g*rsqrt(var+eps), c = be - mean*a ----
__global__ void k_redparams(const float* __restrict__ partials, int nblk,
                            const float* __restrict__ g, const float* __restrict__ be,
                            float* __restrict__ a, float* __restrict__ c) {
    __shared__ float ls[256], lq[256];
    int t = threadIdx.x;
    int col = blockIdx.x;  // 0..127
    float s = 0.f, q = 0.f;
    for (int i = t; i < nblk; i += 256) {
        s += partials[i * 256 + col];
        q += partials[i * 256 + 128 + col];
    }
    ls[t] = s; lq[t] = q;
    __syncthreads();
    for (int off = 128; off > 0; off >>= 1) {
        if (t < off) { ls[t] += ls[t + off]; lq[t] += lq[t + off]; }
        __syncthreads();
    }
    if (t == 0) {
        float mean = ls[0] / (float)NN;
        float var = fmaxf(lq[0] / (float)NN - mean * mean, 0.f);
        float av = g[col] * rsqrtf(var + BN_EPS);
        a[col] = av;
        c[col] = be[col] - mean * av;
    }
}

// ---- stats of z = relu(a2*Y2 + c2) ----
__global__ __launch_bounds__(256) void k_zstats(
    const unsigned short* __restrict__ Y2, const float* __restrict__ a2,
    const float* __restrict__ c2, float* __restrict__ partials)
{
    __shared__ float ls[256], lq[256];
    int t = threadIdx.x;
    int col = t & 127, half = t >> 7;
    float av = a2[col], cv = c2[col];
    float s = 0.f, q = 0.f;
    for (int row = blockIdx.x * 2 + half; row < NN; row += gridDim.x * 2) {
        float z = fmaxf(av * bf2f(Y2[row * DD + col]) + cv, 0.f);
        s += z;
        q += z * z;
    }
    ls[t] = s;
    lq[t] = q;
    __syncthreads();
    if (t < 128) {
        partials[blockIdx.x * 256 + t] = ls[t] + ls[t + 128];
        partials[blockIdx.x * 256 + 128 + t] = lq[t] + lq[t + 128];
    }
}

// ---- out = a3*relu(a2*Y2+c2) + c3, f32 out ----
__global__ __launch_bounds__(256) void k_out(
    const unsigned short* __restrict__ Y2, const float* __restrict__ a2,
    const float* __restrict__ c2, const float* __restrict__ a3,
    const float* __restrict__ c3, float* __restrict__ out)
{
    int g = blockIdx.x * 256 + threadIdx.x;
    int base = g * 4;
    int c0 = base & 127;
    uint2 p = *reinterpret_cast<const uint2*>(Y2 + base);
    float4 av2 = *reinterpret_cast<const float4*>(a2 + c0);
    float4 cv2 = *reinterpret_cast<const float4*>(c2 + c0);
    float4 av3 = *reinterpret_cast<const float4*>(a3 + c0);
    float4 cv3 = *reinterpret_cast<const float4*>(c3 + c0);
    float z0 = fmaxf(av2.x * plo(p.x) + cv2.x, 0.f);
    float z1 = fmaxf(av2.y * phi(p.x) + cv2.y, 0.f);
    float z2 = fmaxf(av2.z * plo(p.y) + cv2.z, 0.f);
    float z3 = fmaxf(av2.w * phi(p.y) + cv2.w, 0.f);
    float4 o;
    o.x = av3.x * z0 + cv3.x;
    o.y = av3.y * z1 + cv3.y;
    o.z = av3.z * z2 + cv3.z;
    o.w = av3.w * z3 + cv3.w;
    *reinterpret_cast<float4*>(out + base) = o;
}

extern "C" void kernel_launch(void* const* d_in, const int* in_sizes, int n_in,
                              void* d_out, int out_size, void* d_ws, size_t ws_size,
                              hipStream_t stream) {
    (void)in_sizes; (void)n_in; (void)out_size; (void)ws_size;
    const float* feats = (const float*)d_in[0];
    const int* src = (const int*)d_in[1];
    const int* dst = (const int*)d_in[2];
    const float* W1 = (const float*)d_in[3];
    const float* b1 = (const float*)d_in[4];
    const float* g1 = (const float*)d_in[5];
    const float* be1 = (const float*)d_in[6];
    const float* W2 = (const float*)d_in[7];
    const float* b2 = (const float*)d_in[8];
    const float* g2 = (const float*)d_in[9];
    const float* be2 = (const float*)d_in[10];
    const float* g3 = (const float*)d_in[11];
    const float* be3 = (const float*)d_in[12];
    float* out = (float*)d_out;

    char* p = (char*)d_ws;
    auto alloc = [&](size_t n) { char* r = p; p += (n + 255) & ~(size_t)255; return r; };
    unsigned int* fb = (unsigned int*)alloc((size_t)NN * 64 * 4);      // packed bf16
    unsigned int* h0 = (unsigned int*)alloc((size_t)NN * 64 * 4);      // packed bf16
    unsigned int* bcur = (unsigned int*)alloc((size_t)NB * 16 * 4);    // line-padded
    unsigned int* tmp = (unsigned int*)alloc((size_t)NB * CAPB * 4);
    unsigned short* Y1 = (unsigned short*)alloc((size_t)NN * DD * 2);
    unsigned short* Y2 = (unsigned short*)alloc((size_t)NN * DD * 2);
    unsigned short* Wt1 = (unsigned short*)alloc((size_t)DD * DD * 2);
    unsigned short* Wt2 = (unsigned short*)alloc((size_t)DD * DD * 2);
    float* partials = (float*)alloc((size_t)784 * 256 * 4);
    float* a1 = (float*)alloc(DD * 4); float* c1 = (float*)alloc(DD * 4);
    float* a2 = (float*)alloc(DD * 4); float* c2 = (float*)alloc(DD * 4);
    float* a3 = (float*)alloc(DD * 4); float* c3 = (float*)alloc(DD * 4);

    k_prep<<<6250, 256, 0, stream>>>(feats, fb, W1, W2, Wt1, Wt2, bcur);
    k_bin<<<NBK, 1024, 0, stream>>>(src, dst, bcur, tmp);
    k_aggmax<<<NB, 512, 0, stream>>>(fb, tmp, bcur, h0);
    // layer 1
    k_gemm<0><<<782, 512, 0, stream>>>((const unsigned short*)h0, Wt1, b1,
                                       nullptr, nullptr, Y1, partials);
    k_redparams<<<128, 256, 0, stream>>>(partials, 782, g1, be1, a1, c1);
    // layer 2 (BN1+ReLU fused into A-load)
    k_gemm<1><<<782, 512, 0, stream>>>(Y1, Wt2, b2, a1, c1, Y2, partials);
    k_redparams<<<128, 256, 0, stream>>>(partials, 782, g2, be2, a2, c2);
    // outer BN over z = relu(a2*Y2+c2)
    k_zstats<<<256, 256, 0, stream>>>(Y2, a2, c2, partials);
    k_redparams<<<128, 256, 0, stream>>>(partials, 256, g3, be3, a3, c3);
    k_out<<<6250, 256, 0, stream>>>(Y2, a2, c2, a3, c3, out);
}

// Round 13
// 252.332 us; speedup vs baseline: 1.1478x; 1.0243x over previous
//
#include <hip/hip_runtime.h>
#include <stdint.h>

// GIN layer, f32 interface. bf16 MFMA GEMMs with BN-stat epilogues.
// R13 = R12 fusion with the wave-decomposition bug fixed: k_agg_gemm's
// phase-3 tile is 32x128, so the 8 waves are partitioned 16rows x 32cols
// each (rl=(wave>>2)*16, nh=(wave&3)*32) — R12 used the 64-row mapping,
// waves 4-7 read hrow OOB and clobbered the next bucket's Y rows.
// Fusion kills the 25.6 MB h0 round-trip + 1 launch and overlaps gemm1
// MFMA with the gather's L2/LLC stalls (R11: gather service rate is the
// aggregation floor). Counting-sort binning: 1 global atomic per
// (block,bucket) (R8: per-lane global atomics ~40us/800k regardless of
// contention).

#define NN 50000
#define NE 800000
#define DD 128
#define BN_EPS 1e-5f
#define NB 1563    // ceil(50000/32) buckets (32 dst nodes each)
#define CAPB 768   // bucket region capacity: mean 512 + ~11 sigma
#define NBK 64     // binning blocks
#define EPB 12500  // edges per binning block (64*12500 = 800000)
#define HS 68      // hrow LDS stride in uints (16B-aligned, bank-safe)

typedef short bf16x8 __attribute__((ext_vector_type(8)));
typedef float f32x4 __attribute__((ext_vector_type(4)));

__device__ __forceinline__ float bf2f(unsigned short u) {
    return __uint_as_float(((unsigned int)u) << 16);
}
__device__ __forceinline__ unsigned short f2bf(float f) {
    unsigned int u = __float_as_uint(f);
    u += 0x7fffu + ((u >> 16) & 1u);  // RNE
    return (unsigned short)(u >> 16);
}
__device__ __forceinline__ float plo(unsigned int p) { return bf2f((unsigned short)(p & 0xffffu)); }
__device__ __forceinline__ float phi(unsigned int p) { return bf2f((unsigned short)(p >> 16)); }

// ---- feats f32 -> bf16 packed; W transposes; cursor init (one launch) ----
__global__ __launch_bounds__(256) void k_prep(
    const float* __restrict__ feats, unsigned int* __restrict__ fb,
    const float* __restrict__ W1, const float* __restrict__ W2,
    unsigned short* __restrict__ Wt1, unsigned short* __restrict__ Wt2,
    unsigned int* __restrict__ bcur)
{
    int g = blockIdx.x * 256 + threadIdx.x;   // 1.6M threads, 4 floats each
    float4 v = *reinterpret_cast<const float4*>(feats + (size_t)g * 4);
    uint2 o;
    o.x = (unsigned int)f2bf(v.x) | ((unsigned int)f2bf(v.y) << 16);
    o.y = (unsigned int)f2bf(v.z) | ((unsigned int)f2bf(v.w) << 16);
    *reinterpret_cast<uint2*>(fb + (size_t)g * 2) = o;
    if (g < 16384) {
        int row = g >> 7, col = g & 127;
        Wt1[col * DD + row] = f2bf(W1[g]);
    } else if (g < 32768) {
        int h = g - 16384;
        int row = h >> 7, col = h & 127;
        Wt2[col * DD + row] = f2bf(W2[h]);
    }
    if (g < NB) bcur[(size_t)g * 16] = (unsigned int)g * CAPB;
}

// ---- edge binning: LDS-staged counting sort, 1 atomic per (block,bucket) ----
// word = src<<16 | dst (both < 65536). bucket = dst>>5. 1024 threads.
__global__ __launch_bounds__(1024) void k_bin(
    const int* __restrict__ src, const int* __restrict__ dst,
    unsigned int* __restrict__ bcur, unsigned int* __restrict__ tmp)
{
    __shared__ unsigned int words[EPB];
    __shared__ unsigned short loff[EPB];
    __shared__ unsigned int lhist[NB];
    __shared__ unsigned int lbase[NB];
    int tid = threadIdx.x;
    int e0 = blockIdx.x * EPB;
    for (int c = tid; c < NB; c += 1024) lhist[c] = 0u;
    __syncthreads();
    for (int i = tid; i < EPB; i += 1024) {
        int d = dst[e0 + i];
        int s = src[e0 + i];
        words[i] = ((unsigned int)s << 16) | (unsigned int)d;
        loff[i] = (unsigned short)atomicAdd(&lhist[d >> 5], 1u);
    }
    __syncthreads();
    for (int c = tid; c < NB; c += 1024) {
        unsigned int cnt = lhist[c];
        lbase[c] = cnt ? atomicAdd(&bcur[(size_t)c * 16], cnt) : 0u;
    }
    __syncthreads();
    for (int i = tid; i < EPB; i += 1024) {
        unsigned int w = words[i];
        int b = (int)((w & 0xffffu) >> 5);
        unsigned int pos = lbase[b] + (unsigned int)loff[i];
        if (pos < (unsigned int)(b + 1) * CAPB) tmp[pos] = w;
    }
}

// ---- fused: per-bucket sort by dst -> register max -> h0 tile in LDS ->
//      32x128 @ 128x128 bf16 MFMA (Y1 + BN-stat partials) ----
// grid = NB, 512 threads = 8 waves. Phase-3 wave map: 16 rows x 32 cols.
__global__ __launch_bounds__(512) void k_agg_gemm(
    const unsigned int* __restrict__ F,   // fb as uint rows of 64
    const unsigned int* __restrict__ tmp,
    const unsigned int* __restrict__ bcur,
    const unsigned short* __restrict__ Wt, const float* __restrict__ bias,
    unsigned short* __restrict__ Y, float* __restrict__ partials)
{
    __shared__ unsigned int sorted[CAPB];
    __shared__ unsigned int hist[32];
    __shared__ unsigned int hbase[33];
    __shared__ unsigned int hrow[32 * HS];   // packed bf16 h0 tile
    __shared__ float lsum[128], lsq[128];
    int tid = threadIdx.x;
    int b = blockIdx.x;
    if (tid < 32) hist[tid] = 0u;
    if (tid >= 256 && tid < 384) { lsum[tid - 256] = 0.f; lsq[tid - 256] = 0.f; }
    __syncthreads();
    unsigned int rb = (unsigned int)b * CAPB;
    unsigned int cnt = bcur[(size_t)b * 16] - rb;
    if (cnt > CAPB) cnt = CAPB;

    // phase 1: load words (coalesced), LDS hist by dst&31 (each thr <=2)
    unsigned int wreg[2]; unsigned short lo[2]; int nw = 0;
    for (unsigned int i = tid; i < cnt; i += 512) {
        unsigned int ww = tmp[rb + i];
        wreg[nw] = ww;
        lo[nw] = (unsigned short)atomicAdd(&hist[ww & 31], 1u);
        nw++;
    }
    __syncthreads();
    if (tid == 0) {
        unsigned int acc = 0;
#pragma unroll
        for (int i = 0; i < 32; ++i) { hbase[i] = acc; acc += hist[i]; }
        hbase[32] = acc;
    }
    __syncthreads();
    for (int k = 0; k < nw; ++k)
        sorted[hbase[wreg[k] & 31] + (unsigned int)lo[k]] = wreg[k];
    __syncthreads();

    // phase 2: wave per 4 dsts; register max over run; h0 row -> LDS tile
    int wave = tid >> 6, lane = tid & 63;
    int n0 = b * 32;
#pragma unroll 1
    for (int dd = wave * 4; dd < wave * 4 + 4; ++dd) {
        int n = n0 + dd;
        if (n >= NN) { hrow[dd * HS + lane] = 0u; continue; }
        int st = (int)hbase[dd], en = (int)hbase[dd + 1];
        float m0 = -3.0e38f, m1 = -3.0e38f;
        int i = st;
        for (; i + 4 <= en; i += 4) {
            unsigned int w0 = sorted[i], w1 = sorted[i + 1];
            unsigned int w2 = sorted[i + 2], w3 = sorted[i + 3];
            unsigned int u0 = F[(w0 >> 16) * 64 + lane];
            unsigned int u1 = F[(w1 >> 16) * 64 + lane];
            unsigned int u2 = F[(w2 >> 16) * 64 + lane];
            unsigned int u3 = F[(w3 >> 16) * 64 + lane];
            m0 = fmaxf(m0, fmaxf(fmaxf(plo(u0), plo(u1)), fmaxf(plo(u2), plo(u3))));
            m1 = fmaxf(m1, fmaxf(fmaxf(phi(u0), phi(u1)), fmaxf(phi(u2), phi(u3))));
        }
        for (; i < en; ++i) {
            unsigned int ww = sorted[i];
            unsigned int u = F[(ww >> 16) * 64 + lane];
            m0 = fmaxf(m0, plo(u));
            m1 = fmaxf(m1, phi(u));
        }
        if (en == st) { m0 = 0.f; m1 = 0.f; }  // no in-edges -> agg = 0
        unsigned int pf = F[n * 64 + lane];
        hrow[dd * HS + lane] = (unsigned int)f2bf(plo(pf) + m0) |
                               ((unsigned int)f2bf(phi(pf) + m1) << 16);
    }
    __syncthreads();

    // phase 3: 32x128 GEMM; wave = 16 rows x 32 cols piece.
    // rows: (wave>>2)*16 (2 groups), cols: (wave&3)*32 (4 groups).
    int quad = lane >> 4, l16 = lane & 15;
    int rl = (wave >> 2) * 16 + l16;          // local A row 0..31
    int nh = (wave & 3) * 32;
    int kq = quad * 8;
    f32x4 acc[2];
#pragma unroll
    for (int j = 0; j < 2; ++j)
#pragma unroll
        for (int r = 0; r < 4; ++r) acc[j][r] = 0.f;
#pragma unroll
    for (int k0 = 0; k0 < 128; k0 += 32) {
        bf16x8 a = *reinterpret_cast<const bf16x8*>(&hrow[rl * HS + ((k0 + kq) >> 1)]);
#pragma unroll
        for (int j = 0; j < 2; ++j) {
            bf16x8 bb = *reinterpret_cast<const bf16x8*>(Wt + (nh + j * 16 + l16) * DD + k0 + kq);
            acc[j] = __builtin_amdgcn_mfma_f32_16x16x32_bf16(a, bb, acc[j], 0, 0, 0);
        }
    }

    int rbase = n0 + (wave >> 2) * 16 + quad * 4;
#pragma unroll
    for (int j = 0; j < 2; ++j) {
        int col = nh + j * 16 + l16;
        float bcol = bias[col];
        float s = 0.f, q = 0.f;
#pragma unroll
        for (int r = 0; r < 4; ++r) {
            int row = rbase + r;
            if (row < NN) {
                float v = acc[j][r] + bcol;
                Y[row * DD + col] = f2bf(v);
                s += v;
                q += v * v;
            }
        }
        s += __shfl_xor(s, 16, 64);
        s += __shfl_xor(s, 32, 64);
        q += __shfl_xor(q, 16, 64);
        q += __shfl_xor(q, 32, 64);
        if (quad == 0) {
            atomicAdd(&lsum[col], s);
            atomicAdd(&lsq[col], q);
        }
    }
    __syncthreads();
    if (tid < 128) {
        partials[blockIdx.x * 256 + tid] = lsum[tid];
        partials[blockIdx.x * 256 + 128 + tid] = lsq[tid];
    }
}

// ---- GEMM2: Y2 = relu(a1*Y1+c1) @ W2 + b2 (bf16 MFMA) + col sum/sumsq ----
// grid 782, block 512 = 8 waves; block covers 64 rows; wave = 16r x 64c.
__global__ __launch_bounds__(512) void k_gemm2(
    const unsigned short* __restrict__ X, const unsigned short* __restrict__ Wt,
    const float* __restrict__ bias, const float* __restrict__ pa,
    const float* __restrict__ pc, unsigned short* __restrict__ Y,
    float* __restrict__ partials)
{
    __shared__ float lsum[128], lsq[128];
    int tid = threadIdx.x;
    if (tid < 128) { lsum[tid] = 0.f; lsq[tid] = 0.f; }
    __syncthreads();
    int wave = tid >> 6, lane = tid & 63;
    int quad = lane >> 4, l16 = lane & 15;
    int m0 = blockIdx.x * 64 + (wave >> 1) * 16;
    int nh = (wave & 1) * 64;
    int myrow = m0 + l16;
    int kq = quad * 8;

    f32x4 acc[4];
#pragma unroll
    for (int j = 0; j < 4; ++j)
#pragma unroll
        for (int r = 0; r < 4; ++r) acc[j][r] = 0.f;

#pragma unroll
    for (int k0 = 0; k0 < 128; k0 += 32) {
        bf16x8 a;
        if (myrow < NN) {
            a = *reinterpret_cast<const bf16x8*>(X + myrow * DD + k0 + kq);
            float4 av0 = *reinterpret_cast<const float4*>(pa + k0 + kq);
            float4 av1 = *reinterpret_cast<const float4*>(pa + k0 + kq + 4);
            float4 cv0 = *reinterpret_cast<const float4*>(pc + k0 + kq);
            float4 cv1 = *reinterpret_cast<const float4*>(pc + k0 + kq + 4);
            float fa[8] = {av0.x, av0.y, av0.z, av0.w, av1.x, av1.y, av1.z, av1.w};
            float fc[8] = {cv0.x, cv0.y, cv0.z, cv0.w, cv1.x, cv1.y, cv1.z, cv1.w};
#pragma unroll
            for (int j = 0; j < 8; ++j) {
                float v = fmaxf(fa[j] * bf2f((unsigned short)a[j]) + fc[j], 0.f);
                a[j] = (short)f2bf(v);
            }
        } else {
#pragma unroll
            for (int j = 0; j < 8; ++j) a[j] = 0;
        }
#pragma unroll
        for (int j = 0; j < 4; ++j) {
            bf16x8 bb = *reinterpret_cast<const bf16x8*>(Wt + (nh + j * 16 + l16) * DD + k0 + kq);
            acc[j] = __builtin_amdgcn_mfma_f32_16x16x32_bf16(a, bb, acc[j], 0, 0, 0);
        }
    }

    int rbase = m0 + quad * 4;
#pragma unroll
    for (int j = 0; j < 4; ++j) {
        int col = nh + j * 16 + l16;
        float bcol = bias[col];
        float s = 0.f, q = 0.f;
#pragma unroll
        for (int r = 0; r < 4; ++r) {
            int row = rbase + r;
            if (row < NN) {
                float v = acc[j][r] + bcol;
                Y[row * DD + col] = f2bf(v);
                s += v;
                q += v * v;
            }
        }
        s += __shfl_xor(s, 16, 64);
        s += __shfl_xor(s, 32, 64);
        q += __shfl_xor(q, 16, 64);
        q += __shfl_xor(q, 32, 64);
        if (quad == 0) {
            atomicAdd(&lsum[col], s);
            atomicAdd(&lsq[col], q);
        }
    }
    __syncthreads();
    if (tid < 128) {
        partials[blockIdx.x * 256 + tid] = lsum[tid];
        partials[blockIdx.x * 256 + 128 + tid] = lsq[tid];
    }
}

// ---- reduce partials + BN affine: a = g*rsqrt(var+eps), c = be - mean*a ----
__global__ void k_redparams(const float* __restrict__ partials, int nblk,
                            const float* __restrict__ g, const float* __restrict__ be,
                            float* __restrict__ a, float* __restrict__ c) {
    __shared__ float ls[256], lq[256];
    int t = threadIdx.x;
    int col = blockIdx.x;  // 0..127
    float s = 0.f, q = 0.f;
    for (int i = t; i < nblk; i += 256) {
        s += partials[i * 256 + col];
        q += partials[i * 256 + 128 + col];
    }
    ls[t] = s; lq[t] = q;
    __syncthreads();
    for (int off = 128; off > 0; off >>= 1) {
        if (t < off) { ls[t] += ls[t + off]; lq[t] += lq[t + off]; }
        __syncthreads();
    }
    if (t == 0) {
        float mean = ls[0] / (float)NN;
        float var = fmaxf(lq[0] / (float)NN - mean * mean, 0.f);
        float av = g[col] * rsqrtf(var + BN_EPS);
        a[col] = av;
        c[col] = be[col] - mean * av;
    }
}

// ---- stats of z = relu(a2*Y2 + c2) ----
__global__ __launch_bounds__(256) void k_zstats(
    const unsigned short* __restrict__ Y2, const float* __restrict__ a2,
    const float* __restrict__ c2, float* __restrict__ partials)
{
    __shared__ float ls[256], lq[256];
    int t = threadIdx.x;
    int col = t & 127, half = t >> 7;
    float av = a2[col], cv = c2[col];
    float s = 0.f, q = 0.f;
    for (int row = blockIdx.x * 2 + half; row < NN; row += gridDim.x * 2) {
        float z = fmaxf(av * bf2f(Y2[row * DD + col]) + cv, 0.f);
        s += z;
        q += z * z;
    }
    ls[t] = s;
    lq[t] = q;
    __syncthreads();
    if (t < 128) {
        partials[blockIdx.x * 256 + t] = ls[t] + ls[t + 128];
        partials[blockIdx.x * 256 + 128 + t] = lq[t] + lq[t + 128];
    }
}

// ---- out = a3*relu(a2*Y2+c2) + c3, f32 out ----
__global__ __launch_bounds__(256) void k_out(
    const unsigned short* __restrict__ Y2, const float* __restrict__ a2,
    const float* __restrict__ c2, const float* __restrict__ a3,
    const float* __restrict__ c3, float* __restrict__ out)
{
    int g = blockIdx.x * 256 + threadIdx.x;
    int base = g * 4;
    int c0 = base & 127;
    uint2 p = *reinterpret_cast<const uint2*>(Y2 + base);
    float4 av2 = *reinterpret_cast<const float4*>(a2 + c0);
    float4 cv2 = *reinterpret_cast<const float4*>(c2 + c0);
    float4 av3 = *reinterpret_cast<const float4*>(a3 + c0);
    float4 cv3 = *reinterpret_cast<const float4*>(c3 + c0);
    float z0 = fmaxf(av2.x * plo(p.x) + cv2.x, 0.f);
    float z1 = fmaxf(av2.y * phi(p.x) + cv2.y, 0.f);
    float z2 = fmaxf(av2.z * plo(p.y) + cv2.z, 0.f);
    float z3 = fmaxf(av2.w * phi(p.y) + cv2.w, 0.f);
    float4 o;
    o.x = av3.x * z0 + cv3.x;
    o.y = av3.y * z1 + cv3.y;
    o.z = av3.z * z2 + cv3.z;
    o.w = av3.w * z3 + cv3.w;
    *reinterpret_cast<float4*>(out + base) = o;
}

extern "C" void kernel_launch(void* const* d_in, const int* in_sizes, int n_in,
                              void* d_out, int out_size, void* d_ws, size_t ws_size,
                              hipStream_t stream) {
    (void)in_sizes; (void)n_in; (void)out_size; (void)ws_size;
    const float* feats = (const float*)d_in[0];
    const int* src = (const int*)d_in[1];
    const int* dst = (const int*)d_in[2];
    const float* W1 = (const float*)d_in[3];
    const float* b1 = (const float*)d_in[4];
    const float* g1 = (const float*)d_in[5];
    const float* be1 = (const float*)d_in[6];
    const float* W2 = (const float*)d_in[7];
    const float* b2 = (const float*)d_in[8];
    const float* g2 = (const float*)d_in[9];
    const float* be2 = (const float*)d_in[10];
    const float* g3 = (const float*)d_in[11];
    const float* be3 = (const float*)d_in[12];
    float* out = (float*)d_out;

    char* p = (char*)d_ws;
    auto alloc = [&](size_t n) { char* r = p; p += (n + 255) & ~(size_t)255; return r; };
    unsigned int* fb = (unsigned int*)alloc((size_t)NN * 64 * 4);      // packed bf16
    unsigned int* bcur = (unsigned int*)alloc((size_t)NB * 16 * 4);    // line-padded
    unsigned int* tmp = (unsigned int*)alloc((size_t)NB * CAPB * 4);
    unsigned short* Y1 = (unsigned short*)alloc((size_t)NN * DD * 2);
    unsigned short* Y2 = (unsigned short*)alloc((size_t)NN * DD * 2);
    unsigned short* Wt1 = (unsigned short*)alloc((size_t)DD * DD * 2);
    unsigned short* Wt2 = (unsigned short*)alloc((size_t)DD * DD * 2);
    float* partials = (float*)alloc((size_t)1568 * 256 * 4);
    float* a1 = (float*)alloc(DD * 4); float* c1 = (float*)alloc(DD * 4);
    float* a2 = (float*)alloc(DD * 4); float* c2 = (float*)alloc(DD * 4);
    float* a3 = (float*)alloc(DD * 4); float* c3 = (float*)alloc(DD * 4);

    k_prep<<<6250, 256, 0, stream>>>(feats, fb, W1, W2, Wt1, Wt2, bcur);
    k_bin<<<NBK, 1024, 0, stream>>>(src, dst, bcur, tmp);
    // fused aggregation + layer-1 GEMM
    k_agg_gemm<<<NB, 512, 0, stream>>>(fb, tmp, bcur, Wt1, b1, Y1, partials);
    k_redparams<<<128, 256, 0, stream>>>(partials, NB, g1, be1, a1, c1);
    // layer 2 (BN1+ReLU fused into A-load)
    k_gemm2<<<782, 512, 0, stream>>>(Y1, Wt2, b2, a1, c1, Y2, partials);
    k_redparams<<<128, 256, 0, stream>>>(partials, 782, g2, be2, a2, c2);
    // outer BN over z = relu(a2*Y2+c2)
    k_zstats<<<256, 256, 0, stream>>>(Y2, a2, c2, partials);
    k_redparams<<<128, 256, 0, stream>>>(partials, 256, g3, be3, a3, c3);
    k_out<<<6250, 256, 0, stream>>>(Y2, a2, c2, a3, c3, out);
}

// Round 14
// 232.037 us; speedup vs baseline: 1.2482x; 1.0875x over previous
//
#include <hip/hip_runtime.h>
#include <stdint.h>

// GIN layer, f32 interface. bf16 MFMA GEMMs with BN-stat epilogues.
// R14: (1) k_bin stages edge words in REGISTERS (fixed-trip unrolled,
// predicated) instead of 75KB LDS - each thread only reuses its own
// entries; (2) k_agg_gemm phase-2 gather unroll 4->8 (more MLP against
// the LLC-random-service stall that sets its floor - R13: 52us, VALU 36%,
// Mfma 1%); (3) k_zstats vectorized (uint 2-col loads, 4 rows/iter).
// Fused agg+gemm1 per 32-node bucket (R13); counting-sort binning with 1
// global atomic per (block,bucket) (R8: per-lane global atomics cost
// ~40us/800k regardless of contention).

#define NN 50000
#define NE 800000
#define DD 128
#define BN_EPS 1e-5f
#define NB 1563    // ceil(50000/32) buckets (32 dst nodes each)
#define CAPB 768   // bucket region capacity: mean 512 + ~11 sigma
#define NBK 64     // binning blocks
#define EPB 12500  // edges per binning block (64*12500 = 800000)
#define HS 68      // hrow LDS stride in uints (16B-aligned, bank-safe)

typedef short bf16x8 __attribute__((ext_vector_type(8)));
typedef float f32x4 __attribute__((ext_vector_type(4)));

__device__ __forceinline__ float bf2f(unsigned short u) {
    return __uint_as_float(((unsigned int)u) << 16);
}
__device__ __forceinline__ unsigned short f2bf(float f) {
    unsigned int u = __float_as_uint(f);
    u += 0x7fffu + ((u >> 16) & 1u);  // RNE
    return (unsigned short)(u >> 16);
}
__device__ __forceinline__ float plo(unsigned int p) { return bf2f((unsigned short)(p & 0xffffu)); }
__device__ __forceinline__ float phi(unsigned int p) { return bf2f((unsigned short)(p >> 16)); }

// ---- feats f32 -> bf16 packed; W transposes; cursor init (one launch) ----
__global__ __launch_bounds__(256) void k_prep(
    const float* __restrict__ feats, unsigned int* __restrict__ fb,
    const float* __restrict__ W1, const float* __restrict__ W2,
    unsigned short* __restrict__ Wt1, unsigned short* __restrict__ Wt2,
    unsigned int* __restrict__ bcur)
{
    int g = blockIdx.x * 256 + threadIdx.x;   // 1.6M threads, 4 floats each
    float4 v = *reinterpret_cast<const float4*>(feats + (size_t)g * 4);
    uint2 o;
    o.x = (unsigned int)f2bf(v.x) | ((unsigned int)f2bf(v.y) << 16);
    o.y = (unsigned int)f2bf(v.z) | ((unsigned int)f2bf(v.w) << 16);
    *reinterpret_cast<uint2*>(fb + (size_t)g * 2) = o;
    if (g < 16384) {
        int row = g >> 7, col = g & 127;
        Wt1[col * DD + row] = f2bf(W1[g]);
    } else if (g < 32768) {
        int h = g - 16384;
        int row = h >> 7, col = h & 127;
        Wt2[col * DD + row] = f2bf(W2[h]);
    }
    if (g < NB) bcur[(size_t)g * 16] = (unsigned int)g * CAPB;
}

// ---- edge binning: register-staged counting sort, 1 atomic/(block,bucket) --
// word = src<<16 | dst (both < 65536). bucket = dst>>5. 1024 threads.
// NW=13 fixed-trip predicated loops keep wreg/lo in VGPRs (no LDS staging).
#define NW 13
__global__ __launch_bounds__(1024) void k_bin(
    const int* __restrict__ src, const int* __restrict__ dst,
    unsigned int* __restrict__ bcur, unsigned int* __restrict__ tmp)
{
    __shared__ unsigned int lhist[NB];
    __shared__ unsigned int lbase[NB];
    int tid = threadIdx.x;
    int e0 = blockIdx.x * EPB;
    for (int c = tid; c < NB; c += 1024) lhist[c] = 0u;
    __syncthreads();
    unsigned int wreg[NW];
    unsigned short lo[NW];
#pragma unroll
    for (int k = 0; k < NW; ++k) {
        int i = tid + k * 1024;
        if (i < EPB) {
            int d = dst[e0 + i];
            int s = src[e0 + i];
            wreg[k] = ((unsigned int)s << 16) | (unsigned int)d;
            lo[k] = (unsigned short)atomicAdd(&lhist[d >> 5], 1u);
        }
    }
    __syncthreads();
    for (int c = tid; c < NB; c += 1024) {
        unsigned int cnt = lhist[c];
        lbase[c] = cnt ? atomicAdd(&bcur[(size_t)c * 16], cnt) : 0u;
    }
    __syncthreads();
#pragma unroll
    for (int k = 0; k < NW; ++k) {
        int i = tid + k * 1024;
        if (i < EPB) {
            unsigned int w = wreg[k];
            int b = (int)((w & 0xffffu) >> 5);
            unsigned int pos = lbase[b] + (unsigned int)lo[k];
            if (pos < (unsigned int)(b + 1) * CAPB) tmp[pos] = w;
        }
    }
}

// ---- fused: per-bucket sort by dst -> register max (unroll 8) ->
//      h0 tile in LDS -> 32x128 @ 128x128 bf16 MFMA (Y1 + BN partials) ----
// grid = NB, 512 threads = 8 waves. Phase-3 wave map: 16 rows x 32 cols.
__global__ __launch_bounds__(512) void k_agg_gemm(
    const unsigned int* __restrict__ F,   // fb as uint rows of 64
    const unsigned int* __restrict__ tmp,
    const unsigned int* __restrict__ bcur,
    const unsigned short* __restrict__ Wt, const float* __restrict__ bias,
    unsigned short* __restrict__ Y, float* __restrict__ partials)
{
    __shared__ unsigned int sorted[CAPB];
    __shared__ unsigned int hist[32];
    __shared__ unsigned int hbase[33];
    __shared__ unsigned int hrow[32 * HS];   // packed bf16 h0 tile
    __shared__ float lsum[128], lsq[128];
    int tid = threadIdx.x;
    int b = blockIdx.x;
    if (tid < 32) hist[tid] = 0u;
    if (tid >= 256 && tid < 384) { lsum[tid - 256] = 0.f; lsq[tid - 256] = 0.f; }
    __syncthreads();
    unsigned int rb = (unsigned int)b * CAPB;
    unsigned int cnt = bcur[(size_t)b * 16] - rb;
    if (cnt > CAPB) cnt = CAPB;

    // phase 1: load words (coalesced), LDS hist by dst&31 (each thr <=2)
    unsigned int wreg[2]; unsigned short lo[2]; int nw = 0;
    for (unsigned int i = tid; i < cnt; i += 512) {
        unsigned int ww = tmp[rb + i];
        wreg[nw] = ww;
        lo[nw] = (unsigned short)atomicAdd(&hist[ww & 31], 1u);
        nw++;
    }
    __syncthreads();
    if (tid == 0) {
        unsigned int acc = 0;
#pragma unroll
        for (int i = 0; i < 32; ++i) { hbase[i] = acc; acc += hist[i]; }
        hbase[32] = acc;
    }
    __syncthreads();
    for (int k = 0; k < nw; ++k)
        sorted[hbase[wreg[k] & 31] + (unsigned int)lo[k]] = wreg[k];
    __syncthreads();

    // phase 2: wave per 4 dsts; register max over run (unroll 8)
    int wave = tid >> 6, lane = tid & 63;
    int n0 = b * 32;
#pragma unroll 1
    for (int dd = wave * 4; dd < wave * 4 + 4; ++dd) {
        int n = n0 + dd;
        if (n >= NN) { hrow[dd * HS + lane] = 0u; continue; }
        unsigned int pfself = F[n * 64 + lane];   // hoisted, independent
        int st = (int)hbase[dd], en = (int)hbase[dd + 1];
        float m0 = -3.0e38f, m1 = -3.0e38f;
        int i = st;
        for (; i + 8 <= en; i += 8) {
            unsigned int w0 = sorted[i],     w1 = sorted[i + 1];
            unsigned int w2 = sorted[i + 2], w3 = sorted[i + 3];
            unsigned int w4 = sorted[i + 4], w5 = sorted[i + 5];
            unsigned int w6 = sorted[i + 6], w7 = sorted[i + 7];
            unsigned int u0 = F[(w0 >> 16) * 64 + lane];
            unsigned int u1 = F[(w1 >> 16) * 64 + lane];
            unsigned int u2 = F[(w2 >> 16) * 64 + lane];
            unsigned int u3 = F[(w3 >> 16) * 64 + lane];
            unsigned int u4 = F[(w4 >> 16) * 64 + lane];
            unsigned int u5 = F[(w5 >> 16) * 64 + lane];
            unsigned int u6 = F[(w6 >> 16) * 64 + lane];
            unsigned int u7 = F[(w7 >> 16) * 64 + lane];
            float a0 = fmaxf(plo(u0), plo(u1)), a1 = fmaxf(plo(u2), plo(u3));
            float a2 = fmaxf(plo(u4), plo(u5)), a3 = fmaxf(plo(u6), plo(u7));
            float b0 = fmaxf(phi(u0), phi(u1)), b1 = fmaxf(phi(u2), phi(u3));
            float b2 = fmaxf(phi(u4), phi(u5)), b3 = fmaxf(phi(u6), phi(u7));
            m0 = fmaxf(m0, fmaxf(fmaxf(a0, a1), fmaxf(a2, a3)));
            m1 = fmaxf(m1, fmaxf(fmaxf(b0, b1), fmaxf(b2, b3)));
        }
        for (; i + 4 <= en; i += 4) {
            unsigned int w0 = sorted[i],     w1 = sorted[i + 1];
            unsigned int w2 = sorted[i + 2], w3 = sorted[i + 3];
            unsigned int u0 = F[(w0 >> 16) * 64 + lane];
            unsigned int u1 = F[(w1 >> 16) * 64 + lane];
            unsigned int u2 = F[(w2 >> 16) * 64 + lane];
            unsigned int u3 = F[(w3 >> 16) * 64 + lane];
            m0 = fmaxf(m0, fmaxf(fmaxf(plo(u0), plo(u1)), fmaxf(plo(u2), plo(u3))));
            m1 = fmaxf(m1, fmaxf(fmaxf(phi(u0), phi(u1)), fmaxf(phi(u2), phi(u3))));
        }
        for (; i < en; ++i) {
            unsigned int ww = sorted[i];
            unsigned int u = F[(ww >> 16) * 64 + lane];
            m0 = fmaxf(m0, plo(u));
            m1 = fmaxf(m1, phi(u));
        }
        if (en == st) { m0 = 0.f; m1 = 0.f; }  // no in-edges -> agg = 0
        hrow[dd * HS + lane] = (unsigned int)f2bf(plo(pfself) + m0) |
                               ((unsigned int)f2bf(phi(pfself) + m1) << 16);
    }
    __syncthreads();

    // phase 3: 32x128 GEMM; wave = 16 rows x 32 cols piece.
    int quad = lane >> 4, l16 = lane & 15;
    int rl = (wave >> 2) * 16 + l16;          // local A row 0..31
    int nh = (wave & 3) * 32;
    int kq = quad * 8;
    f32x4 acc[2];
#pragma unroll
    for (int j = 0; j < 2; ++j)
#pragma unroll
        for (int r = 0; r < 4; ++r) acc[j][r] = 0.f;
#pragma unroll
    for (int k0 = 0; k0 < 128; k0 += 32) {
        bf16x8 a = *reinterpret_cast<const bf16x8*>(&hrow[rl * HS + ((k0 + kq) >> 1)]);
#pragma unroll
        for (int j = 0; j < 2; ++j) {
            bf16x8 bb = *reinterpret_cast<const bf16x8*>(Wt + (nh + j * 16 + l16) * DD + k0 + kq);
            acc[j] = __builtin_amdgcn_mfma_f32_16x16x32_bf16(a, bb, acc[j], 0, 0, 0);
        }
    }

    int rbase = n0 + (wave >> 2) * 16 + quad * 4;
#pragma unroll
    for (int j = 0; j < 2; ++j) {
        int col = nh + j * 16 + l16;
        float bcol = bias[col];
        float s = 0.f, q = 0.f;
#pragma unroll
        for (int r = 0; r < 4; ++r) {
            int row = rbase + r;
            if (row < NN) {
                float v = acc[j][r] + bcol;
                Y[row * DD + col] = f2bf(v);
                s += v;
                q += v * v;
            }
        }
        s += __shfl_xor(s, 16, 64);
        s += __shfl_xor(s, 32, 64);
        q += __shfl_xor(q, 16, 64);
        q += __shfl_xor(q, 32, 64);
        if (quad == 0) {
            atomicAdd(&lsum[col], s);
            atomicAdd(&lsq[col], q);
        }
    }
    __syncthreads();
    if (tid < 128) {
        partials[blockIdx.x * 256 + tid] = lsum[tid];
        partials[blockIdx.x * 256 + 128 + tid] = lsq[tid];
    }
}

// ---- GEMM2: Y2 = relu(a1*Y1+c1) @ W2 + b2 (bf16 MFMA) + col sum/sumsq ----
// grid 782, block 512 = 8 waves; block covers 64 rows; wave = 16r x 64c.
__global__ __launch_bounds__(512) void k_gemm2(
    const unsigned short* __restrict__ X, const unsigned short* __restrict__ Wt,
    const float* __restrict__ bias, const float* __restrict__ pa,
    const float* __restrict__ pc, unsigned short* __restrict__ Y,
    float* __restrict__ partials)
{
    __shared__ float lsum[128], lsq[128];
    int tid = threadIdx.x;
    if (tid < 128) { lsum[tid] = 0.f; lsq[tid] = 0.f; }
    __syncthreads();
    int wave = tid >> 6, lane = tid & 63;
    int quad = lane >> 4, l16 = lane & 15;
    int m0 = blockIdx.x * 64 + (wave >> 1) * 16;
    int nh = (wave & 1) * 64;
    int myrow = m0 + l16;
    int kq = quad * 8;

    f32x4 acc[4];
#pragma unroll
    for (int j = 0; j < 4; ++j)
#pragma unroll
        for (int r = 0; r < 4; ++r) acc[j][r] = 0.f;

#pragma unroll
    for (int k0 = 0; k0 < 128; k0 += 32) {
        bf16x8 a;
        if (myrow < NN) {
            a = *reinterpret_cast<const bf16x8*>(X + myrow * DD + k0 + kq);
            float4 av0 = *reinterpret_cast<const float4*>(pa + k0 + kq);
            float4 av1 = *reinterpret_cast<const float4*>(pa + k0 + kq + 4);
            float4 cv0 = *reinterpret_cast<const float4*>(pc + k0 + kq);
            float4 cv1 = *reinterpret_cast<const float4*>(pc + k0 + kq + 4);
            float fa[8] = {av0.x, av0.y, av0.z, av0.w, av1.x, av1.y, av1.z, av1.w};
            float fc[8] = {cv0.x, cv0.y, cv0.z, cv0.w, cv1.x, cv1.y, cv1.z, cv1.w};
#pragma unroll
            for (int j = 0; j < 8; ++j) {
                float v = fmaxf(fa[j] * bf2f((unsigned short)a[j]) + fc[j], 0.f);
                a[j] = (short)f2bf(v);
            }
        } else {
#pragma unroll
            for (int j = 0; j < 8; ++j) a[j] = 0;
        }
#pragma unroll
        for (int j = 0; j < 4; ++j) {
            bf16x8 bb = *reinterpret_cast<const bf16x8*>(Wt + (nh + j * 16 + l16) * DD + k0 + kq);
            acc[j] = __builtin_amdgcn_mfma_f32_16x16x32_bf16(a, bb, acc[j], 0, 0, 0);
        }
    }

    int rbase = m0 + quad * 4;
#pragma unroll
    for (int j = 0; j < 4; ++j) {
        int col = nh + j * 16 + l16;
        float bcol = bias[col];
        float s = 0.f, q = 0.f;
#pragma unroll
        for (int r = 0; r < 4; ++r) {
            int row = rbase + r;
            if (row < NN) {
                float v = acc[j][r] + bcol;
                Y[row * DD + col] = f2bf(v);
                s += v;
                q += v * v;
            }
        }
        s += __shfl_xor(s, 16, 64);
        s += __shfl_xor(s, 32, 64);
        q += __shfl_xor(q, 16, 64);
        q += __shfl_xor(q, 32, 64);
        if (quad == 0) {
            atomicAdd(&lsum[col], s);
            atomicAdd(&lsq[col], q);
        }
    }
    __syncthreads();
    if (tid < 128) {
        partials[blockIdx.x * 256 + tid] = lsum[tid];
        partials[blockIdx.x * 256 + 128 + tid] = lsq[tid];
    }
}

// ---- reduce partials + BN affine: a = g*rsqrt(var+eps), c = be - mean*a ----
__global__ void k_redparams(const float* __restrict__ partials, int nblk,
                            const float* __restrict__ g, const float* __restrict__ be,
                            float* __restrict__ a, float* __restrict__ c) {
    __shared__ float ls[256], lq[256];
    int t = threadIdx.x;
    int col = blockIdx.x;  // 0..127
    float s = 0.f, q = 0.f;
    for (int i = t; i < nblk; i += 256) {
        s += partials[i * 256 + col];
        q += partials[i * 256 + 128 + col];
    }
    ls[t] = s; lq[t] = q;
    __syncthreads();
    for (int off = 128; off > 0; off >>= 1) {
        if (t < off) { ls[t] += ls[t + off]; lq[t] += lq[t + off]; }
        __syncthreads();
    }
    if (t == 0) {
        float mean = ls[0] / (float)NN;
        float var = fmaxf(lq[0] / (float)NN - mean * mean, 0.f);
        float av = g[col] * rsqrtf(var + BN_EPS);
        a[col] = av;
        c[col] = be[col] - mean * av;
    }
}

// ---- stats of z = relu(a2*Y2 + c2), vectorized (2 cols/thread) ----
__global__ __launch_bounds__(256) void k_zstats(
    const unsigned int* __restrict__ Y2u, const float* __restrict__ a2,
    const float* __restrict__ c2, float* __restrict__ partials)
{
    __shared__ float ls[256], lq[256];
    int t = threadIdx.x;
    int cp = t & 63;           // uint col index (covers cols 2cp, 2cp+1)
    int r4 = t >> 6;           // 0..3
    int col0 = cp * 2;
    float av0 = a2[col0],     cv0 = c2[col0];
    float av1 = a2[col0 + 1], cv1 = c2[col0 + 1];
    float s0 = 0.f, q0 = 0.f, s1 = 0.f, q1 = 0.f;
    for (int row = blockIdx.x * 4 + r4; row < NN; row += gridDim.x * 4) {
        unsigned int p = Y2u[row * 64 + cp];
        float z0 = fmaxf(av0 * plo(p) + cv0, 0.f);
        float z1 = fmaxf(av1 * phi(p) + cv1, 0.f);
        s0 += z0; q0 += z0 * z0;
        s1 += z1; q1 += z1 * z1;
    }
    ls[t] = s0; lq[t] = q0;
    __syncthreads();
    if (t < 64) {
        float S = ls[t] + ls[t + 64] + ls[t + 128] + ls[t + 192];
        float Q = lq[t] + lq[t + 64] + lq[t + 128] + lq[t + 192];
        partials[blockIdx.x * 256 + t * 2] = S;
        partials[blockIdx.x * 256 + 128 + t * 2] = Q;
    }
    __syncthreads();
    ls[t] = s1; lq[t] = q1;
    __syncthreads();
    if (t < 64) {
        float S = ls[t] + ls[t + 64] + ls[t + 128] + ls[t + 192];
        float Q = lq[t] + lq[t + 64] + lq[t + 128] + lq[t + 192];
        partials[blockIdx.x * 256 + t * 2 + 1] = S;
        partials[blockIdx.x * 256 + 128 + t * 2 + 1] = Q;
    }
}

// ---- out = a3*relu(a2*Y2+c2) + c3, f32 out ----
__global__ __launch_bounds__(256) void k_out(
    const unsigned short* __restrict__ Y2, const float* __restrict__ a2,
    const float* __restrict__ c2, const float* __restrict__ a3,
    const float* __restrict__ c3, float* __restrict__ out)
{
    int g = blockIdx.x * 256 + threadIdx.x;
    int base = g * 4;
    int c0 = base & 127;
    uint2 p = *reinterpret_cast<const uint2*>(Y2 + base);
    float4 av2 = *reinterpret_cast<const float4*>(a2 + c0);
    float4 cv2 = *reinterpret_cast<const float4*>(c2 + c0);
    float4 av3 = *reinterpret_cast<const float4*>(a3 + c0);
    float4 cv3 = *reinterpret_cast<const float4*>(c3 + c0);
    float z0 = fmaxf(av2.x * plo(p.x) + cv2.x, 0.f);
    float z1 = fmaxf(av2.y * phi(p.x) + cv2.y, 0.f);
    float z2 = fmaxf(av2.z * plo(p.y) + cv2.z, 0.f);
    float z3 = fmaxf(av2.w * phi(p.y) + cv2.w, 0.f);
    float4 o;
    o.x = av3.x * z0 + cv3.x;
    o.y = av3.y * z1 + cv3.y;
    o.z = av3.z * z2 + cv3.z;
    o.w = av3.w * z3 + cv3.w;
    *reinterpret_cast<float4*>(out + base) = o;
}

extern "C" void kernel_launch(void* const* d_in, const int* in_sizes, int n_in,
                              void* d_out, int out_size, void* d_ws, size_t ws_size,
                              hipStream_t stream) {
    (void)in_sizes; (void)n_in; (void)out_size; (void)ws_size;
    const float* feats = (const float*)d_in[0];
    const int* src = (const int*)d_in[1];
    const int* dst = (const int*)d_in[2];
    const float* W1 = (const float*)d_in[3];
    const float* b1 = (const float*)d_in[4];
    const float* g1 = (const float*)d_in[5];
    const float* be1 = (const float*)d_in[6];
    const float* W2 = (const float*)d_in[7];
    const float* b2 = (const float*)d_in[8];
    const float* g2 = (const float*)d_in[9];
    const float* be2 = (const float*)d_in[10];
    const float* g3 = (const float*)d_in[11];
    const float* be3 = (const float*)d_in[12];
    float* out = (float*)d_out;

    char* p = (char*)d_ws;
    auto alloc = [&](size_t n) { char* r = p; p += (n + 255) & ~(size_t)255; return r; };
    unsigned int* fb = (unsigned int*)alloc((size_t)NN * 64 * 4);      // packed bf16
    unsigned int* bcur = (unsigned int*)alloc((size_t)NB * 16 * 4);    // line-padded
    unsigned int* tmp = (unsigned int*)alloc((size_t)NB * CAPB * 4);
    unsigned short* Y1 = (unsigned short*)alloc((size_t)NN * DD * 2);
    unsigned short* Y2 = (unsigned short*)alloc((size_t)NN * DD * 2);
    unsigned short* Wt1 = (unsigned short*)alloc((size_t)DD * DD * 2);
    unsigned short* Wt2 = (unsigned short*)alloc((size_t)DD * DD * 2);
    float* partials = (float*)alloc((size_t)1568 * 256 * 4);
    float* a1 = (float*)alloc(DD * 4); float* c1 = (float*)alloc(DD * 4);
    float* a2 = (float*)alloc(DD * 4); float* c2 = (float*)alloc(DD * 4);
    float* a3 = (float*)alloc(DD * 4); float* c3 = (float*)alloc(DD * 4);

    k_prep<<<6250, 256, 0, stream>>>(feats, fb, W1, W2, Wt1, Wt2, bcur);
    k_bin<<<NBK, 1024, 0, stream>>>(src, dst, bcur, tmp);
    // fused aggregation + layer-1 GEMM
    k_agg_gemm<<<NB, 512, 0, stream>>>(fb, tmp, bcur, Wt1, b1, Y1, partials);
    k_redparams<<<128, 256, 0, stream>>>(partials, NB, g1, be1, a1, c1);
    // layer 2 (BN1+ReLU fused into A-load)
    k_gemm2<<<782, 512, 0, stream>>>(Y1, Wt2, b2, a1, c1, Y2, partials);
    k_redparams<<<128, 256, 0, stream>>>(partials, 782, g2, be2, a2, c2);
    // outer BN over z = relu(a2*Y2+c2)
    k_zstats<<<256, 256, 0, stream>>>((const unsigned int*)Y2, a2, c2, partials);
    k_redparams<<<128, 256, 0, stream>>>(partials, 256, g3, be3, a3, c3);
    k_out<<<6250, 256, 0, stream>>>(Y2, a2, c2, a3, c3, out);
}